// Round 1
// baseline (2020.297 us; speedup 1.0000x reference)
//
#include <hip/hip_runtime.h>
#include <hip/hip_bf16.h>

// ---- geometry (fixed by the problem) ----
// B=2, C=768, T=8, H=24, W=24, nh=12, e=64, n=16, s=576, M=n*s=9216
#define CDIM 768
#define NHEAD 12
#define EDIM 64
#define TDIM 8
#define SDIM 576
#define NROW 16          // B*T
#define MDIM 9216        // NROW*SDIM
#define QKVN 2304

typedef __attribute__((ext_vector_type(4))) float f32x4;
typedef __bf16 bf16x8 __attribute__((ext_vector_type(8)));
typedef unsigned short u16;
typedef __attribute__((ext_vector_type(8))) unsigned short u16x8;

__device__ inline float bf2f(u16 u) {
  union { unsigned int i; float f; } x; x.i = ((unsigned int)u) << 16; return x.f;
}
__device__ inline u16 f2bf(float f) {
  union { float f; unsigned int i; } x; x.f = f;
  unsigned int i = x.i;
  return (u16)((i + 0x7FFFu + ((i >> 16) & 1u)) >> 16);
}

// ---------------- cs = cond @ norm_w^T + 1  (2 x 768) ----------------
__global__ __launch_bounds__(256) void cs_kernel(const float* __restrict__ cond,
                                                 const float* __restrict__ nw,
                                                 float* __restrict__ cs) {
  int idx = blockIdx.x * 256 + threadIdx.x;      // 0..1535
  int b = idx / CDIM, c = idx % CDIM;
  const float* cr = cond + (size_t)b * CDIM;
  const float* wr = nw + (size_t)c * CDIM;
  float s = 1.0f;
  for (int j = 0; j < CDIM; j += 4) {
    float4 a = *(const float4*)(cr + j);
    float4 w = *(const float4*)(wr + j);
    s = fmaf(a.x, w.x, s); s = fmaf(a.y, w.y, s);
    s = fmaf(a.z, w.z, s); s = fmaf(a.w, w.w, s);
  }
  cs[idx] = s;
}

// ---------------- RMS-norm * cs -> xn (M, C) bf16 ----------------
// block (64 hw-lanes, 4 c-groups); grid (9 hw-chunks, 16 n)
__global__ __launch_bounds__(256) void norm_kernel(const float* __restrict__ x,
                                                   const float* __restrict__ cs,
                                                   u16* __restrict__ xn) {
  int n = blockIdx.y;
  int hw0 = blockIdx.x * 64;
  int b = n >> 3, t = n & 7;
  int tx = threadIdx.x, ty = threadIdx.y;
  const float* xb = x + ((size_t)b * CDIM * TDIM + t) * SDIM;  // + c*TDIM*SDIM + hw
  float acc = 0.0f;
  for (int c = ty; c < CDIM; c += 4) {
    float v = xb[(size_t)c * (TDIM * SDIM) + hw0 + tx];
    acc = fmaf(v, v, acc);
  }
  __shared__ float red[4][64];
  __shared__ float rfac[64];
  red[ty][tx] = acc;
  __syncthreads();
  if (ty == 0) {
    float s = red[0][tx] + red[1][tx] + red[2][tx] + red[3][tx];
    rfac[tx] = rsqrtf(s * (1.0f / (float)CDIM) + 1e-6f);
  }
  __syncthreads();
  float rf = rfac[tx];
  const float* csb = cs + (size_t)b * CDIM;
  u16* xr = xn + ((size_t)n * SDIM + hw0 + tx) * CDIM;
  for (int c = ty; c < CDIM; c += 4) {
    float v = xb[(size_t)c * (TDIM * SDIM) + hw0 + tx];
    xr[c] = f2bf(v * csb[c] * rf);
  }
}

// ---------------- f32 -> bf16 weight convert ----------------
__global__ __launch_bounds__(256) void convert_kernel(const float* __restrict__ src,
                                                      u16* __restrict__ dst, int count4) {
  int i = blockIdx.x * 256 + threadIdx.x;
  if (i < count4) {
    float4 v = *(const float4*)(src + (size_t)i * 4);
    u16* d = dst + (size_t)i * 4;
    d[0] = f2bf(v.x); d[1] = f2bf(v.y); d[2] = f2bf(v.z); d[3] = f2bf(v.w);
  }
}

// ---------------- shared MFMA GEMM core: C = A(M,K) * B(N,K)^T ----------------
// 128x128 tile, 4 waves in 2x2, each wave 64x64 via 4x4 16x16x32 frags
#define LDST 56   // bf16 elems per LDS row (112B: 16B-aligned, 2-way max bank alias)

__device__ __forceinline__ void gemm_bt_core(const u16* __restrict__ A,
                                             const u16* __restrict__ B,
                                             int K, int m0, int n0, int tid,
                                             u16* ldsA, u16* ldsB,
                                             f32x4 acc[4][4]) {
  int lane = tid & 63;
  int wid = tid >> 6;
  int wm = (wid >> 1) * 64, wn = (wid & 1) * 64;
  int lr = lane & 15, lk = (lane >> 4) * 8;
  for (int k0 = 0; k0 < K; k0 += 32) {
    #pragma unroll
    for (int i = tid; i < 512; i += 256) {
      int row = i >> 2, seg = i & 3;
      *(int4*)&ldsA[row * LDST + seg * 8] = *(const int4*)(A + (size_t)(m0 + row) * K + k0 + seg * 8);
      *(int4*)&ldsB[row * LDST + seg * 8] = *(const int4*)(B + (size_t)(n0 + row) * K + k0 + seg * 8);
    }
    __syncthreads();
    bf16x8 af[4], bfr[4];
    #pragma unroll
    for (int i = 0; i < 4; i++) af[i]  = *(const bf16x8*)&ldsA[(wm + i * 16 + lr) * LDST + lk];
    #pragma unroll
    for (int j = 0; j < 4; j++) bfr[j] = *(const bf16x8*)&ldsB[(wn + j * 16 + lr) * LDST + lk];
    #pragma unroll
    for (int i = 0; i < 4; i++)
      #pragma unroll
      for (int j = 0; j < 4; j++)
        acc[i][j] = __builtin_amdgcn_mfma_f32_16x16x32_bf16(af[i], bfr[j], acc[i][j], 0, 0, 0);
    __syncthreads();
  }
}

// ---------------- QKV GEMM: xn(M,768) @ wq(2304,768)^T, scatter epilogue ----------------
__global__ __launch_bounds__(256) void gemm_qkv(const u16* __restrict__ xn,
                                                const u16* __restrict__ wq,
                                                u16* __restrict__ q,
                                                u16* __restrict__ k,
                                                u16* __restrict__ vt) {
  __shared__ u16 ldsA[128 * LDST];
  __shared__ u16 ldsB[128 * LDST];
  f32x4 acc[4][4] = {};
  int tid = threadIdx.x;
  int m0 = blockIdx.y * 128, n0 = blockIdx.x * 128;
  gemm_bt_core(xn, wq, CDIM, m0, n0, tid, ldsA, ldsB, acc);
  int lane = tid & 63, wid = tid >> 6;
  int wm = (wid >> 1) * 64, wn = (wid & 1) * 64;
  int lr = lane & 15, rb = (lane >> 4) * 4;
  int part = n0 / CDIM;   // uniform per block (128 | 768)
  #pragma unroll
  for (int i = 0; i < 4; i++)
    #pragma unroll
    for (int j = 0; j < 4; j++)
      #pragma unroll
      for (int r = 0; r < 4; r++) {
        int m = m0 + wm + i * 16 + rb + r;
        int jj = n0 + wn + j * 16 + lr;
        int nidx = m / SDIM, hw = m % SDIM;
        int rem = jj - part * CDIM;
        int h = rem >> 6, e = rem & 63;
        u16 val = f2bf(acc[i][j][r]);
        if (part == 0)      q[((size_t)(nidx * NHEAD + h) * SDIM + hw) * EDIM + e] = val;
        else if (part == 1) k[((size_t)(nidx * NHEAD + h) * SDIM + hw) * EDIM + e] = val;
        else                vt[((size_t)(nidx * NHEAD + h) * EDIM + e) * SDIM + hw] = val;
      }
}

// ---------------- cosine-norm + RoPE on q,k in place ----------------
// block (64 lanes = e, 4 rows); grid 110592/4
__global__ __launch_bounds__(256) void rope_kernel(u16* __restrict__ q, u16* __restrict__ k,
                                                   const float* __restrict__ pos,
                                                   const float* __restrict__ freqs,
                                                   const float* __restrict__ scale) {
  int row = blockIdx.x * 4 + threadIdx.y;   // (n*12+h)*576 + s
  int e = threadIdx.x;
  int sp = row % SDIM;
  int nh_ = row / SDIM;
  int h = nh_ % NHEAD;
  int n = nh_ / NHEAD;
  int b = n >> 3;
  float p0 = pos[((size_t)b * SDIM + sp) * 2 + 0];
  float p1 = pos[((size_t)b * SDIM + sp) * 2 + 1];
  float cth = 1.0f, sth = 0.0f;
  if (e < 32) {
    int jj = e & 15;
    float th = (jj < 8) ? p0 * freqs[h * 8 + jj] : p1 * freqs[h * 8 + jj - 8];
    cth = cosf(th); sth = sinf(th);
  }
  float sq = sqrtf(scale[h]);
  #pragma unroll
  for (int pass = 0; pass < 2; pass++) {
    u16* base = (pass ? k : q) + (size_t)row * EDIM;
    float v = bf2f(base[e]);
    float ss = v * v;
    #pragma unroll
    for (int m = 1; m < 64; m <<= 1) ss += __shfl_xor(ss, m);
    float qn = v * (sq * rsqrtf(ss + 1e-6f));
    float pr = __shfl_xor(qn, 16);
    float outv;
    if (e < 16)      outv = qn * cth - pr * sth;
    else if (e < 32) outv = qn * cth + pr * sth;
    else             outv = qn;
    base[e] = f2bf(outv);
  }
}

// ---------------- attention (vector f32, full softmax) ----------------
// grid (36 q-tiles, 192 n*h); block 256 = 16 rows x 16 lanes
__global__ __launch_bounds__(256) void attn_kernel(const u16* __restrict__ q,
                                                   const u16* __restrict__ k,
                                                   const u16* __restrict__ vt,
                                                   u16* __restrict__ o) {
  __shared__ float s_lds[16][592];
  __shared__ float inv_sum[16];
  int q0 = blockIdx.x * 16;
  int nh_ = blockIdx.y;
  int n = nh_ / NHEAD, h = nh_ % NHEAD;
  int tid = threadIdx.x;
  int r = tid >> 4, cg = tid & 15;

  float qreg[64];
  const u16* qrow = q + ((size_t)nh_ * SDIM + q0 + r) * EDIM;
  #pragma unroll
  for (int e0 = 0; e0 < 64; e0 += 8) {
    u16x8 u = *(const u16x8*)(qrow + e0);
    #pragma unroll
    for (int x2 = 0; x2 < 8; x2++) qreg[e0 + x2] = bf2f(u[x2]);
  }

  const u16* kb = k + (size_t)nh_ * SDIM * EDIM;
  float mx = -1e30f;
  for (int c = cg; c < SDIM; c += 16) {
    const u16* kr = kb + (size_t)c * EDIM;
    float dot = 0.0f;
    #pragma unroll
    for (int e0 = 0; e0 < 64; e0 += 8) {
      u16x8 u = *(const u16x8*)(kr + e0);
      #pragma unroll
      for (int x2 = 0; x2 < 8; x2++) dot = fmaf(qreg[e0 + x2], bf2f(u[x2]), dot);
    }
    s_lds[r][c] = dot;
    mx = fmaxf(mx, dot);
  }
  #pragma unroll
  for (int m = 1; m < 16; m <<= 1) mx = fmaxf(mx, __shfl_xor(mx, m));
  float sum = 0.0f;
  for (int c = cg; c < SDIM; c += 16) {
    float p = __expf(s_lds[r][c] - mx);
    s_lds[r][c] = p;
    sum += p;
  }
  #pragma unroll
  for (int m = 1; m < 16; m <<= 1) sum += __shfl_xor(sum, m);
  if (cg == 0) inv_sum[r] = 1.0f / sum;
  __syncthreads();

  float accv[4] = {0.0f, 0.0f, 0.0f, 0.0f};
  const u16* vb = vt + (size_t)nh_ * EDIM * SDIM;
  for (int c = 0; c < SDIM; c += 8) {
    float p[8];
    *(float4*)&p[0] = *(const float4*)&s_lds[r][c];
    *(float4*)&p[4] = *(const float4*)&s_lds[r][c + 4];
    #pragma unroll
    for (int ii = 0; ii < 4; ii++) {
      u16x8 u = *(const u16x8*)(vb + (size_t)(cg + 16 * ii) * SDIM + c);
      #pragma unroll
      for (int x2 = 0; x2 < 8; x2++) accv[ii] = fmaf(p[x2], bf2f(u[x2]), accv[ii]);
    }
  }
  float inv = inv_sum[r];
  u16* orow = o + ((size_t)n * SDIM + q0 + r) * CDIM + h * EDIM;
  #pragma unroll
  for (int ii = 0; ii < 4; ii++) orow[cg + 16 * ii] = f2bf(accv[ii] * inv);
}

// ---------------- out projection + skip: out = o @ wo^T + x ----------------
__global__ __launch_bounds__(256) void gemm_proj(const u16* __restrict__ o,
                                                 const u16* __restrict__ wo,
                                                 const float* __restrict__ x,
                                                 float* __restrict__ out) {
  __shared__ u16 ldsA[128 * LDST];
  __shared__ u16 ldsB[128 * LDST];
  f32x4 acc[4][4] = {};
  int tid = threadIdx.x;
  int m0 = blockIdx.y * 128, n0 = blockIdx.x * 128;
  gemm_bt_core(o, wo, CDIM, m0, n0, tid, ldsA, ldsB, acc);
  int lane = tid & 63, wid = tid >> 6;
  int wm = (wid >> 1) * 64, wn = (wid & 1) * 64;
  int lr = lane & 15, rb = (lane >> 4) * 4;
  #pragma unroll
  for (int i = 0; i < 4; i++)
    #pragma unroll
    for (int j = 0; j < 4; j++)
      #pragma unroll
      for (int r = 0; r < 4; r++) {
        int m = m0 + wm + i * 16 + rb + r;
        int jj = n0 + wn + j * 16 + lr;
        int nidx = m / SDIM, hw = m % SDIM;
        int b = nidx >> 3, t = nidx & 7;
        size_t oi = ((size_t)(b * CDIM + jj) * TDIM + t) * SDIM + hw;
        out[oi] = acc[i][j][r] + x[oi];
      }
}

extern "C" void kernel_launch(void* const* d_in, const int* in_sizes, int n_in,
                              void* d_out, int out_size, void* d_ws, size_t ws_size,
                              hipStream_t stream) {
  const float* x      = (const float*)d_in[0];
  const float* pos    = (const float*)d_in[1];
  const float* cond   = (const float*)d_in[2];
  const float* norm_w = (const float*)d_in[3];
  const float* qkv_w  = (const float*)d_in[4];
  const float* scale  = (const float*)d_in[5];
  const float* out_w  = (const float*)d_in[6];
  const float* freqs  = (const float*)d_in[7];
  float* out = (float*)d_out;

  char* ws = (char*)d_ws;
  size_t off = 0;
  auto alloc = [&](size_t bytes) -> char* {
    char* p = ws + off;
    off = (off + bytes + 255) & ~(size_t)255;
    return p;
  };
  float* cs  = (float*)alloc(2 * CDIM * sizeof(float));
  u16* wq    = (u16*)alloc((size_t)QKVN * CDIM * 2);
  u16* wo    = (u16*)alloc((size_t)CDIM * CDIM * 2);
  u16* xn    = (u16*)alloc((size_t)MDIM * CDIM * 2);
  u16* qb    = (u16*)alloc((size_t)MDIM * CDIM * 2);
  u16* kb    = (u16*)alloc((size_t)MDIM * CDIM * 2);
  u16* vt    = (u16*)alloc((size_t)MDIM * CDIM * 2);
  u16* ob    = (u16*)alloc((size_t)MDIM * CDIM * 2);

  convert_kernel<<<dim3((QKVN * CDIM / 4 + 255) / 256), dim3(256), 0, stream>>>(qkv_w, wq, QKVN * CDIM / 4);
  convert_kernel<<<dim3((CDIM * CDIM / 4 + 255) / 256), dim3(256), 0, stream>>>(out_w, wo, CDIM * CDIM / 4);
  cs_kernel<<<dim3(6), dim3(256), 0, stream>>>(cond, norm_w, cs);
  norm_kernel<<<dim3(9, 16), dim3(64, 4), 0, stream>>>(x, cs, xn);
  gemm_qkv<<<dim3(QKVN / 128, MDIM / 128), dim3(256), 0, stream>>>(xn, wq, qb, kb, vt);
  rope_kernel<<<dim3(NROW * NHEAD * SDIM / 4), dim3(64, 4), 0, stream>>>(qb, kb, pos, freqs, scale);
  attn_kernel<<<dim3(SDIM / 16, NROW * NHEAD), dim3(256), 0, stream>>>(qb, kb, vt, ob);
  gemm_proj<<<dim3(CDIM / 128, MDIM / 128), dim3(256), 0, stream>>>(ob, wo, x, out);
}

// Round 2
// 447.316 us; speedup vs baseline: 4.5165x; 4.5165x over previous
//
#include <hip/hip_runtime.h>
#include <hip/hip_bf16.h>

// ---- geometry (fixed by the problem) ----
// B=2, C=768, T=8, H=24, W=24, nh=12, e=64, n=16, s=576, M=n*s=9216
#define CDIM 768
#define NHEAD 12
#define EDIM 64
#define TDIM 8
#define SDIM 576
#define NROW 16          // B*T
#define MDIM 9216        // NROW*SDIM
#define QKVN 2304

typedef __attribute__((ext_vector_type(4))) float f32x4;
typedef __bf16 bf16x8 __attribute__((ext_vector_type(8)));
typedef unsigned short u16;
typedef __attribute__((ext_vector_type(8))) unsigned short u16x8;

__device__ inline float bf2f(u16 u) {
  union { unsigned int i; float f; } x; x.i = ((unsigned int)u) << 16; return x.f;
}
__device__ inline u16 f2bf(float f) {
  union { float f; unsigned int i; } x; x.f = f;
  unsigned int i = x.i;
  return (u16)((i + 0x7FFFu + ((i >> 16) & 1u)) >> 16);
}

// ---------------- cs = cond @ norm_w^T + 1  (2 x 768) ----------------
__global__ __launch_bounds__(256) void cs_kernel(const float* __restrict__ cond,
                                                 const float* __restrict__ nw,
                                                 float* __restrict__ cs) {
  int idx = blockIdx.x * 256 + threadIdx.x;      // 0..1535
  int b = idx / CDIM, c = idx % CDIM;
  const float* cr = cond + (size_t)b * CDIM;
  const float* wr = nw + (size_t)c * CDIM;
  float s = 1.0f;
  for (int j = 0; j < CDIM; j += 4) {
    float4 a = *(const float4*)(cr + j);
    float4 w = *(const float4*)(wr + j);
    s = fmaf(a.x, w.x, s); s = fmaf(a.y, w.y, s);
    s = fmaf(a.z, w.z, s); s = fmaf(a.w, w.w, s);
  }
  cs[idx] = s;
}

// ---------------- RMS-norm * cs -> xn (M, C) bf16 ----------------
__global__ __launch_bounds__(256) void norm_kernel(const float* __restrict__ x,
                                                   const float* __restrict__ cs,
                                                   u16* __restrict__ xn) {
  int n = blockIdx.y;
  int hw0 = blockIdx.x * 64;
  int b = n >> 3, t = n & 7;
  int tx = threadIdx.x, ty = threadIdx.y;
  const float* xb = x + ((size_t)b * CDIM * TDIM + t) * SDIM;
  float acc = 0.0f;
  for (int c = ty; c < CDIM; c += 4) {
    float v = xb[(size_t)c * (TDIM * SDIM) + hw0 + tx];
    acc = fmaf(v, v, acc);
  }
  __shared__ float red[4][64];
  __shared__ float rfac[64];
  red[ty][tx] = acc;
  __syncthreads();
  if (ty == 0) {
    float s = red[0][tx] + red[1][tx] + red[2][tx] + red[3][tx];
    rfac[tx] = rsqrtf(s * (1.0f / (float)CDIM) + 1e-6f);
  }
  __syncthreads();
  float rf = rfac[tx];
  const float* csb = cs + (size_t)b * CDIM;
  u16* xr = xn + ((size_t)n * SDIM + hw0 + tx) * CDIM;
  for (int c = ty; c < CDIM; c += 4) {
    float v = xb[(size_t)c * (TDIM * SDIM) + hw0 + tx];
    xr[c] = f2bf(v * csb[c] * rf);
  }
}

// ---------------- f32 -> bf16 weight convert ----------------
__global__ __launch_bounds__(256) void convert_kernel(const float* __restrict__ src,
                                                      u16* __restrict__ dst, int count4) {
  int i = blockIdx.x * 256 + threadIdx.x;
  if (i < count4) {
    float4 v = *(const float4*)(src + (size_t)i * 4);
    u16* d = dst + (size_t)i * 4;
    d[0] = f2bf(v.x); d[1] = f2bf(v.y); d[2] = f2bf(v.z); d[3] = f2bf(v.w);
  }
}

// ---------------- shared MFMA GEMM core: C = A(M,K) * B(N,K)^T ----------------
#define LDST 56

__device__ __forceinline__ void gemm_bt_core(const u16* __restrict__ A,
                                             const u16* __restrict__ B,
                                             int K, int m0, int n0, int tid,
                                             u16* ldsA, u16* ldsB,
                                             f32x4 acc[4][4]) {
  int lane = tid & 63;
  int wid = tid >> 6;
  int wm = (wid >> 1) * 64, wn = (wid & 1) * 64;
  int lr = lane & 15, lk = (lane >> 4) * 8;
  for (int k0 = 0; k0 < K; k0 += 32) {
    #pragma unroll
    for (int i = tid; i < 512; i += 256) {
      int row = i >> 2, seg = i & 3;
      *(int4*)&ldsA[row * LDST + seg * 8] = *(const int4*)(A + (size_t)(m0 + row) * K + k0 + seg * 8);
      *(int4*)&ldsB[row * LDST + seg * 8] = *(const int4*)(B + (size_t)(n0 + row) * K + k0 + seg * 8);
    }
    __syncthreads();
    bf16x8 af[4], bfr[4];
    #pragma unroll
    for (int i = 0; i < 4; i++) af[i]  = *(const bf16x8*)&ldsA[(wm + i * 16 + lr) * LDST + lk];
    #pragma unroll
    for (int j = 0; j < 4; j++) bfr[j] = *(const bf16x8*)&ldsB[(wn + j * 16 + lr) * LDST + lk];
    #pragma unroll
    for (int i = 0; i < 4; i++)
      #pragma unroll
      for (int j = 0; j < 4; j++)
        acc[i][j] = __builtin_amdgcn_mfma_f32_16x16x32_bf16(af[i], bfr[j], acc[i][j], 0, 0, 0);
    __syncthreads();
  }
}

// ---------------- QKV GEMM with scatter epilogue ----------------
__global__ __launch_bounds__(256) void gemm_qkv(const u16* __restrict__ xn,
                                                const u16* __restrict__ wq,
                                                u16* __restrict__ q,
                                                u16* __restrict__ k,
                                                u16* __restrict__ vt) {
  __shared__ u16 ldsA[128 * LDST];
  __shared__ u16 ldsB[128 * LDST];
  f32x4 acc[4][4] = {};
  int tid = threadIdx.x;
  int m0 = blockIdx.y * 128, n0 = blockIdx.x * 128;
  gemm_bt_core(xn, wq, CDIM, m0, n0, tid, ldsA, ldsB, acc);
  int lane = tid & 63, wid = tid >> 6;
  int wm = (wid >> 1) * 64, wn = (wid & 1) * 64;
  int lr = lane & 15, rb = (lane >> 4) * 4;
  int part = n0 / CDIM;
  #pragma unroll
  for (int i = 0; i < 4; i++)
    #pragma unroll
    for (int j = 0; j < 4; j++)
      #pragma unroll
      for (int r = 0; r < 4; r++) {
        int m = m0 + wm + i * 16 + rb + r;
        int jj = n0 + wn + j * 16 + lr;
        int nidx = m / SDIM, hw = m % SDIM;
        int rem = jj - part * CDIM;
        int h = rem >> 6, e = rem & 63;
        u16 val = f2bf(acc[i][j][r]);
        if (part == 0)      q[((size_t)(nidx * NHEAD + h) * SDIM + hw) * EDIM + e] = val;
        else if (part == 1) k[((size_t)(nidx * NHEAD + h) * SDIM + hw) * EDIM + e] = val;
        else                vt[((size_t)(nidx * NHEAD + h) * EDIM + e) * SDIM + hw] = val;
      }
}

// ---------------- cosine-norm + RoPE on q,k in place ----------------
__global__ __launch_bounds__(256) void rope_kernel(u16* __restrict__ q, u16* __restrict__ k,
                                                   const float* __restrict__ pos,
                                                   const float* __restrict__ freqs,
                                                   const float* __restrict__ scale) {
  int row = blockIdx.x * 4 + threadIdx.y;   // (n*12+h)*576 + s
  int e = threadIdx.x;
  int sp = row % SDIM;
  int nh_ = row / SDIM;
  int h = nh_ % NHEAD;
  int n = nh_ / NHEAD;
  int b = n >> 3;
  float p0 = pos[((size_t)b * SDIM + sp) * 2 + 0];
  float p1 = pos[((size_t)b * SDIM + sp) * 2 + 1];
  float cth = 1.0f, sth = 0.0f;
  if (e < 32) {
    int jj = e & 15;
    float th = (jj < 8) ? p0 * freqs[h * 8 + jj] : p1 * freqs[h * 8 + jj - 8];
    cth = cosf(th); sth = sinf(th);
  }
  float sq = sqrtf(scale[h]);
  #pragma unroll
  for (int pass = 0; pass < 2; pass++) {
    u16* base = (pass ? k : q) + (size_t)row * EDIM;
    float v = bf2f(base[e]);
    float ss = v * v;
    #pragma unroll
    for (int m = 1; m < 64; m <<= 1) ss += __shfl_xor(ss, m);
    float qn = v * (sq * rsqrtf(ss + 1e-6f));
    float pr = __shfl_xor(qn, 16);
    float outv;
    if (e < 16)      outv = qn * cth - pr * sth;
    else if (e < 32) outv = qn * cth + pr * sth;
    else             outv = qn;
    base[e] = f2bf(outv);
  }
}

// ---------------- MFMA flash attention ----------------
// grid (9 q-tiles of 64, 192 n*h); block 256 = 4 independent waves, 16 q-rows each.
// Per KV-tile (64 cols): QK^T (8 mfma) -> online softmax -> P to wave-private LDS
// (stride 72 elems = 144B: 16B-aligned, conflict-free b128 reads) -> PV (8 mfma,
// V streamed from pre-transposed vt). No barriers: LDS is wave-private, DS in-order.
__global__ __launch_bounds__(256) void attn_mfma(const u16* __restrict__ q,
                                                 const u16* __restrict__ k,
                                                 const u16* __restrict__ vt,
                                                 u16* __restrict__ o) {
  __shared__ u16 p_lds[4][16][72];
  int nh_ = blockIdx.y;
  int q0 = blockIdx.x * 64;
  int n = nh_ / NHEAD, h = nh_ % NHEAD;
  int tid = threadIdx.x;
  int wid = tid >> 6, lane = tid & 63;
  int lr = lane & 15, lg = lane >> 4;

  const u16* qrow = q + ((size_t)nh_ * SDIM + q0 + wid * 16 + lr) * EDIM;
  bf16x8 qa[2];
  qa[0] = *(const bf16x8*)(qrow + lg * 8);
  qa[1] = *(const bf16x8*)(qrow + 32 + lg * 8);

  const u16* kb = k + (size_t)nh_ * SDIM * EDIM;
  const u16* vb = vt + (size_t)nh_ * EDIM * SDIM;

  float mrow[4], lrow[4];
  f32x4 oacc[4] = {};
  #pragma unroll
  for (int r = 0; r < 4; r++) { mrow[r] = -1e30f; lrow[r] = 0.0f; }

  for (int kt = 0; kt < 9; kt++) {
    int s0 = kt * 64;
    // ---- QK^T: S[16 q][64 col] ----
    f32x4 sfr[4] = {};
    #pragma unroll
    for (int j = 0; j < 4; j++) {
      const u16* krow = kb + (size_t)(s0 + j * 16 + lr) * EDIM + lg * 8;
      bf16x8 kf0 = *(const bf16x8*)(krow);
      bf16x8 kf1 = *(const bf16x8*)(krow + 32);
      sfr[j] = __builtin_amdgcn_mfma_f32_16x16x32_bf16(qa[0], kf0, sfr[j], 0, 0, 0);
      sfr[j] = __builtin_amdgcn_mfma_f32_16x16x32_bf16(qa[1], kf1, sfr[j], 0, 0, 0);
    }
    // ---- online softmax (rows lane-local: row = lg*4+r, col = lr) ----
    float nm[4], sc[4];
    #pragma unroll
    for (int r = 0; r < 4; r++) {
      float tm = fmaxf(fmaxf(sfr[0][r], sfr[1][r]), fmaxf(sfr[2][r], sfr[3][r]));
      #pragma unroll
      for (int m = 1; m < 16; m <<= 1) tm = fmaxf(tm, __shfl_xor(tm, m));
      nm[r] = fmaxf(mrow[r], tm);
      sc[r] = __expf(mrow[r] - nm[r]);
      mrow[r] = nm[r];
    }
    #pragma unroll
    for (int r = 0; r < 4; r++) {
      float s = 0.0f;
      #pragma unroll
      for (int j = 0; j < 4; j++) {
        float p = __expf(sfr[j][r] - nm[r]);
        p_lds[wid][lg * 4 + r][j * 16 + lr] = f2bf(p);
        s += p;
      }
      #pragma unroll
      for (int m = 1; m < 16; m <<= 1) s += __shfl_xor(s, m);
      lrow[r] = lrow[r] * sc[r] + s;
      oacc[0][r] *= sc[r]; oacc[1][r] *= sc[r];
      oacc[2][r] *= sc[r]; oacc[3][r] *= sc[r];
    }
    // ---- PV: O += P(16x64) @ V(64x64), V from vt (e-major, contiguous in s) ----
    #pragma unroll
    for (int ks = 0; ks < 2; ks++) {
      bf16x8 pa = *(const bf16x8*)&p_lds[wid][lr][ks * 32 + lg * 8];
      #pragma unroll
      for (int et = 0; et < 4; et++) {
        const u16* vrow = vb + (size_t)(et * 16 + lr) * SDIM + s0 + ks * 32 + lg * 8;
        bf16x8 vf = *(const bf16x8*)(vrow);
        oacc[et] = __builtin_amdgcn_mfma_f32_16x16x32_bf16(pa, vf, oacc[et], 0, 0, 0);
      }
    }
  }
  // ---- epilogue: divide by l, store ----
  u16* ob = o + ((size_t)n * SDIM + q0 + wid * 16) * CDIM + h * EDIM;
  #pragma unroll
  for (int r = 0; r < 4; r++) {
    float inv = 1.0f / lrow[r];
    #pragma unroll
    for (int et = 0; et < 4; et++)
      ob[(size_t)(lg * 4 + r) * CDIM + et * 16 + lr] = f2bf(oacc[et][r] * inv);
  }
}

// ---------------- out projection + skip: out = o @ wo^T + x ----------------
__global__ __launch_bounds__(256) void gemm_proj(const u16* __restrict__ o,
                                                 const u16* __restrict__ wo,
                                                 const float* __restrict__ x,
                                                 float* __restrict__ out) {
  __shared__ u16 ldsA[128 * LDST];
  __shared__ u16 ldsB[128 * LDST];
  f32x4 acc[4][4] = {};
  int tid = threadIdx.x;
  int m0 = blockIdx.y * 128, n0 = blockIdx.x * 128;
  gemm_bt_core(o, wo, CDIM, m0, n0, tid, ldsA, ldsB, acc);
  int lane = tid & 63, wid = tid >> 6;
  int wm = (wid >> 1) * 64, wn = (wid & 1) * 64;
  int lr = lane & 15, rb = (lane >> 4) * 4;
  #pragma unroll
  for (int i = 0; i < 4; i++)
    #pragma unroll
    for (int j = 0; j < 4; j++)
      #pragma unroll
      for (int r = 0; r < 4; r++) {
        int m = m0 + wm + i * 16 + rb + r;
        int jj = n0 + wn + j * 16 + lr;
        int nidx = m / SDIM, hw = m % SDIM;
        int b = nidx >> 3, t = nidx & 7;
        size_t oi = ((size_t)(b * CDIM + jj) * TDIM + t) * SDIM + hw;
        out[oi] = acc[i][j][r] + x[oi];
      }
}

extern "C" void kernel_launch(void* const* d_in, const int* in_sizes, int n_in,
                              void* d_out, int out_size, void* d_ws, size_t ws_size,
                              hipStream_t stream) {
  const float* x      = (const float*)d_in[0];
  const float* pos    = (const float*)d_in[1];
  const float* cond   = (const float*)d_in[2];
  const float* norm_w = (const float*)d_in[3];
  const float* qkv_w  = (const float*)d_in[4];
  const float* scale  = (const float*)d_in[5];
  const float* out_w  = (const float*)d_in[6];
  const float* freqs  = (const float*)d_in[7];
  float* out = (float*)d_out;

  char* ws = (char*)d_ws;
  size_t off = 0;
  auto alloc = [&](size_t bytes) -> char* {
    char* p = ws + off;
    off = (off + bytes + 255) & ~(size_t)255;
    return p;
  };
  float* cs  = (float*)alloc(2 * CDIM * sizeof(float));
  u16* wq    = (u16*)alloc((size_t)QKVN * CDIM * 2);
  u16* wo    = (u16*)alloc((size_t)CDIM * CDIM * 2);
  u16* xn    = (u16*)alloc((size_t)MDIM * CDIM * 2);
  u16* qb    = (u16*)alloc((size_t)MDIM * CDIM * 2);
  u16* kb    = (u16*)alloc((size_t)MDIM * CDIM * 2);
  u16* vt    = (u16*)alloc((size_t)MDIM * CDIM * 2);
  u16* ob    = (u16*)alloc((size_t)MDIM * CDIM * 2);

  convert_kernel<<<dim3((QKVN * CDIM / 4 + 255) / 256), dim3(256), 0, stream>>>(qkv_w, wq, QKVN * CDIM / 4);
  convert_kernel<<<dim3((CDIM * CDIM / 4 + 255) / 256), dim3(256), 0, stream>>>(out_w, wo, CDIM * CDIM / 4);
  cs_kernel<<<dim3(6), dim3(256), 0, stream>>>(cond, norm_w, cs);
  norm_kernel<<<dim3(9, 16), dim3(64, 4), 0, stream>>>(x, cs, xn);
  gemm_qkv<<<dim3(QKVN / 128, MDIM / 128), dim3(256), 0, stream>>>(xn, wq, qb, kb, vt);
  rope_kernel<<<dim3(NROW * NHEAD * SDIM / 4), dim3(64, 4), 0, stream>>>(qb, kb, pos, freqs, scale);
  attn_mfma<<<dim3(SDIM / 64, NROW * NHEAD), dim3(256), 0, stream>>>(qb, kb, vt, ob);
  gemm_proj<<<dim3(CDIM / 128, MDIM / 128), dim3(256), 0, stream>>>(ob, wo, x, out);
}

// Round 3
// 336.974 us; speedup vs baseline: 5.9954x; 1.3274x over previous
//
#include <hip/hip_runtime.h>
#include <hip/hip_bf16.h>

// ---- geometry (fixed by the problem) ----
// B=2, C=768, T=8, H=24, W=24, nh=12, e=64, n=16, s=576, M=n*s=9216
#define CDIM 768
#define NHEAD 12
#define EDIM 64
#define TDIM 8
#define SDIM 576
#define NROW 16          // B*T
#define MDIM 9216        // NROW*SDIM
#define QKVN 2304

typedef __attribute__((ext_vector_type(4))) float f32x4;
typedef __bf16 bf16x8 __attribute__((ext_vector_type(8)));
typedef unsigned short u16;
typedef __attribute__((ext_vector_type(8))) unsigned short u16x8;

__device__ inline float bf2f(u16 u) {
  union { unsigned int i; float f; } x; x.i = ((unsigned int)u) << 16; return x.f;
}
__device__ inline u16 f2bf(float f) {
  union { float f; unsigned int i; } x; x.f = f;
  unsigned int i = x.i;
  return (u16)((i + 0x7FFFu + ((i >> 16) & 1u)) >> 16);
}

// ---------------- cs = cond @ norm_w^T + 1  (2 x 768) ----------------
__global__ __launch_bounds__(256) void cs_kernel(const float* __restrict__ cond,
                                                 const float* __restrict__ nw,
                                                 float* __restrict__ cs) {
  int idx = blockIdx.x * 256 + threadIdx.x;      // 0..1535
  int b = idx / CDIM, c = idx % CDIM;
  const float* cr = cond + (size_t)b * CDIM;
  const float* wr = nw + (size_t)c * CDIM;
  float s = 1.0f;
  for (int j = 0; j < CDIM; j += 4) {
    float4 a = *(const float4*)(cr + j);
    float4 w = *(const float4*)(wr + j);
    s = fmaf(a.x, w.x, s); s = fmaf(a.y, w.y, s);
    s = fmaf(a.z, w.z, s); s = fmaf(a.w, w.w, s);
  }
  cs[idx] = s;
}

// ---------------- RMS-norm * cs -> xn (M, C) bf16, one-pass via LDS ----------------
// grid (36 hw-chunks of 16, 16 n); block (16 hw, 16 c-groups)
__global__ __launch_bounds__(256) void norm_kernel(const float* __restrict__ x,
                                                   const float* __restrict__ cs,
                                                   u16* __restrict__ xn) {
  __shared__ float xs[16][772];    // [hw][c], pad 772: write stride %32 = 4 -> 2-way max
  __shared__ float red[16][17];
  __shared__ float rfac[16];
  int n = blockIdx.y;
  int hw0 = blockIdx.x * 16;
  int b = n >> 3, t = n & 7;
  int tx = threadIdx.x, ty = threadIdx.y;
  const float* xb = x + ((size_t)b * CDIM * TDIM + t) * SDIM;
  float acc = 0.0f;
  for (int c = ty; c < CDIM; c += 16) {
    float v = xb[(size_t)c * (TDIM * SDIM) + hw0 + tx];
    xs[tx][c] = v;
    acc = fmaf(v, v, acc);
  }
  red[ty][tx] = acc;
  __syncthreads();
  if (ty == 0) {
    float s = 0.0f;
    #pragma unroll
    for (int j = 0; j < 16; j++) s += red[j][tx];
    rfac[tx] = rsqrtf(s * (1.0f / (float)CDIM) + 1e-6f);
  }
  __syncthreads();
  const float* csb = cs + (size_t)b * CDIM;
  int flat = ty * 16 + tx;
  #pragma unroll
  for (int i = 0; i < 6; i++) {
    int idx = i * 256 + flat;           // 0..1535 = 16 rows * 96 vec8-segs
    int row = idx / 96;
    int cseg = idx - row * 96;
    int c0 = cseg * 8;
    float rf = rfac[row];
    float4 a0 = *(const float4*)&xs[row][c0];
    float4 a1 = *(const float4*)&xs[row][c0 + 4];
    float4 w0 = *(const float4*)(csb + c0);
    float4 w1 = *(const float4*)(csb + c0 + 4);
    u16x8 ov;
    ov[0] = f2bf(a0.x * w0.x * rf); ov[1] = f2bf(a0.y * w0.y * rf);
    ov[2] = f2bf(a0.z * w0.z * rf); ov[3] = f2bf(a0.w * w0.w * rf);
    ov[4] = f2bf(a1.x * w1.x * rf); ov[5] = f2bf(a1.y * w1.y * rf);
    ov[6] = f2bf(a1.z * w1.z * rf); ov[7] = f2bf(a1.w * w1.w * rf);
    *(u16x8*)(xn + ((size_t)n * SDIM + hw0 + row) * CDIM + c0) = ov;
  }
}

// ---------------- f32 -> bf16 weight convert ----------------
__global__ __launch_bounds__(256) void convert_kernel(const float* __restrict__ src,
                                                      u16* __restrict__ dst, int count4) {
  int i = blockIdx.x * 256 + threadIdx.x;
  if (i < count4) {
    float4 v = *(const float4*)(src + (size_t)i * 4);
    u16* d = dst + (size_t)i * 4;
    d[0] = f2bf(v.x); d[1] = f2bf(v.y); d[2] = f2bf(v.z); d[3] = f2bf(v.w);
  }
}

// ---------------- shared MFMA GEMM core: C = A(M,K) * B(N,K)^T ----------------
#define LDST 56

__device__ __forceinline__ void gemm_bt_core(const u16* __restrict__ A,
                                             const u16* __restrict__ B,
                                             int K, int m0, int n0, int tid,
                                             u16* ldsA, u16* ldsB,
                                             f32x4 acc[4][4]) {
  int lane = tid & 63;
  int wid = tid >> 6;
  int wm = (wid >> 1) * 64, wn = (wid & 1) * 64;
  int lr = lane & 15, lk = (lane >> 4) * 8;
  for (int k0 = 0; k0 < K; k0 += 32) {
    #pragma unroll
    for (int i = tid; i < 512; i += 256) {
      int row = i >> 2, seg = i & 3;
      *(int4*)&ldsA[row * LDST + seg * 8] = *(const int4*)(A + (size_t)(m0 + row) * K + k0 + seg * 8);
      *(int4*)&ldsB[row * LDST + seg * 8] = *(const int4*)(B + (size_t)(n0 + row) * K + k0 + seg * 8);
    }
    __syncthreads();
    bf16x8 af[4], bfr[4];
    #pragma unroll
    for (int i = 0; i < 4; i++) af[i]  = *(const bf16x8*)&ldsA[(wm + i * 16 + lr) * LDST + lk];
    #pragma unroll
    for (int j = 0; j < 4; j++) bfr[j] = *(const bf16x8*)&ldsB[(wn + j * 16 + lr) * LDST + lk];
    #pragma unroll
    for (int i = 0; i < 4; i++)
      #pragma unroll
      for (int j = 0; j < 4; j++)
        acc[i][j] = __builtin_amdgcn_mfma_f32_16x16x32_bf16(af[i], bfr[j], acc[i][j], 0, 0, 0);
    __syncthreads();
  }
}

// ---------------- QKV GEMM with scatter epilogue ----------------
__global__ __launch_bounds__(256) void gemm_qkv(const u16* __restrict__ xn,
                                                const u16* __restrict__ wq,
                                                u16* __restrict__ q,
                                                u16* __restrict__ k,
                                                u16* __restrict__ vt) {
  __shared__ u16 ldsA[128 * LDST];
  __shared__ u16 ldsB[128 * LDST];
  f32x4 acc[4][4] = {};
  int tid = threadIdx.x;
  int m0 = blockIdx.y * 128, n0 = blockIdx.x * 128;
  gemm_bt_core(xn, wq, CDIM, m0, n0, tid, ldsA, ldsB, acc);
  int lane = tid & 63, wid = tid >> 6;
  int wm = (wid >> 1) * 64, wn = (wid & 1) * 64;
  int lr = lane & 15, rb = (lane >> 4) * 4;
  int part = n0 / CDIM;
  #pragma unroll
  for (int i = 0; i < 4; i++)
    #pragma unroll
    for (int j = 0; j < 4; j++)
      #pragma unroll
      for (int r = 0; r < 4; r++) {
        int m = m0 + wm + i * 16 + rb + r;
        int jj = n0 + wn + j * 16 + lr;
        int nidx = m / SDIM, hw = m % SDIM;
        int rem = jj - part * CDIM;
        int h = rem >> 6, e = rem & 63;
        u16 val = f2bf(acc[i][j][r]);
        if (part == 0)      q[((size_t)(nidx * NHEAD + h) * SDIM + hw) * EDIM + e] = val;
        else if (part == 1) k[((size_t)(nidx * NHEAD + h) * SDIM + hw) * EDIM + e] = val;
        else                vt[((size_t)(nidx * NHEAD + h) * EDIM + e) * SDIM + hw] = val;
      }
}

// ---------------- cosine-norm + RoPE on q,k in place ----------------
__global__ __launch_bounds__(256) void rope_kernel(u16* __restrict__ q, u16* __restrict__ k,
                                                   const float* __restrict__ pos,
                                                   const float* __restrict__ freqs,
                                                   const float* __restrict__ scale) {
  int row = blockIdx.x * 4 + threadIdx.y;   // (n*12+h)*576 + s
  int e = threadIdx.x;
  int sp = row % SDIM;
  int nh_ = row / SDIM;
  int h = nh_ % NHEAD;
  int n = nh_ / NHEAD;
  int b = n >> 3;
  float p0 = pos[((size_t)b * SDIM + sp) * 2 + 0];
  float p1 = pos[((size_t)b * SDIM + sp) * 2 + 1];
  float cth = 1.0f, sth = 0.0f;
  if (e < 32) {
    int jj = e & 15;
    float th = (jj < 8) ? p0 * freqs[h * 8 + jj] : p1 * freqs[h * 8 + jj - 8];
    cth = cosf(th); sth = sinf(th);
  }
  float sq = sqrtf(scale[h]);
  #pragma unroll
  for (int pass = 0; pass < 2; pass++) {
    u16* base = (pass ? k : q) + (size_t)row * EDIM;
    float v = bf2f(base[e]);
    float ss = v * v;
    #pragma unroll
    for (int m = 1; m < 64; m <<= 1) ss += __shfl_xor(ss, m);
    float qn = v * (sq * rsqrtf(ss + 1e-6f));
    float pr = __shfl_xor(qn, 16);
    float outv;
    if (e < 16)      outv = qn * cth - pr * sth;
    else if (e < 32) outv = qn * cth + pr * sth;
    else             outv = qn;
    base[e] = f2bf(outv);
  }
}

// ---------------- MFMA flash attention v2 ----------------
// grid (3 q-tiles of 192, 192 heads) with bijective XCD-chunk swizzle (576 = 8*72):
// each head's 3 blocks land on one XCD -> K/V L2-resident. Block = 4 waves, each
// wave owns 48 q-rows (3 row-frags). Per KV-tile (64 cols): V loads issued first
// (fly under QK^T+softmax), K-next issued before PV (flies under PV MFMAs).
__global__ __launch_bounds__(256) void attn_mfma(const u16* __restrict__ q,
                                                 const u16* __restrict__ k,
                                                 const u16* __restrict__ vt,
                                                 u16* __restrict__ o) {
  __shared__ u16 p_lds[4][48][72];
  int L = blockIdx.y * 3 + blockIdx.x;           // 0..575
  int cid = (L & 7) * 72 + (L >> 3);             // XCD-chunked remap
  int nh_ = cid / 3;
  int qt = cid - nh_ * 3;
  int n = nh_ / NHEAD, h = nh_ - n * NHEAD;
  int tid = threadIdx.x;
  int wid = tid >> 6, lane = tid & 63;
  int lr = lane & 15, lg = lane >> 4;
  int qbase = qt * 192 + wid * 48;

  const u16* qp = q + ((size_t)nh_ * SDIM + qbase) * EDIM;
  bf16x8 qa[3][2];
  #pragma unroll
  for (int f = 0; f < 3; f++) {
    qa[f][0] = *(const bf16x8*)(qp + (size_t)(f * 16 + lr) * EDIM + lg * 8);
    qa[f][1] = *(const bf16x8*)(qp + (size_t)(f * 16 + lr) * EDIM + 32 + lg * 8);
  }
  const u16* kb = k + (size_t)nh_ * SDIM * EDIM;
  const u16* vb = vt + (size_t)nh_ * EDIM * SDIM;

  float mrow[3][4], lrow[3][4];
  f32x4 oacc[3][4] = {};
  #pragma unroll
  for (int f = 0; f < 3; f++)
    #pragma unroll
    for (int r = 0; r < 4; r++) { mrow[f][r] = -1e30f; lrow[f][r] = 0.0f; }

  bf16x8 kf[4][2];
  #pragma unroll
  for (int j = 0; j < 4; j++) {
    const u16* kr = kb + (size_t)(j * 16 + lr) * EDIM + lg * 8;
    kf[j][0] = *(const bf16x8*)kr;
    kf[j][1] = *(const bf16x8*)(kr + 32);
  }

  #pragma unroll 1
  for (int kt = 0; kt < 9; kt++) {
    int s0 = kt * 64;
    // ---- V loads for this tile: in flight during QK^T + softmax ----
    bf16x8 vf[2][4];
    #pragma unroll
    for (int ks = 0; ks < 2; ks++)
      #pragma unroll
      for (int et = 0; et < 4; et++)
        vf[ks][et] = *(const bf16x8*)(vb + (size_t)(et * 16 + lr) * SDIM + s0 + ks * 32 + lg * 8);
    // ---- QK^T + online softmax, per row-frag f ----
    #pragma unroll
    for (int f = 0; f < 3; f++) {
      f32x4 sfr[4] = {};
      #pragma unroll
      for (int j = 0; j < 4; j++) {
        sfr[j] = __builtin_amdgcn_mfma_f32_16x16x32_bf16(qa[f][0], kf[j][0], sfr[j], 0, 0, 0);
        sfr[j] = __builtin_amdgcn_mfma_f32_16x16x32_bf16(qa[f][1], kf[j][1], sfr[j], 0, 0, 0);
      }
      #pragma unroll
      for (int r = 0; r < 4; r++) {
        float tm = fmaxf(fmaxf(sfr[0][r], sfr[1][r]), fmaxf(sfr[2][r], sfr[3][r]));
        #pragma unroll
        for (int m = 1; m < 16; m <<= 1) tm = fmaxf(tm, __shfl_xor(tm, m));
        float nm = fmaxf(mrow[f][r], tm);
        float sc = __expf(mrow[f][r] - nm);
        mrow[f][r] = nm;
        float s = 0.0f;
        #pragma unroll
        for (int j = 0; j < 4; j++) {
          float p = __expf(sfr[j][r] - nm);
          p_lds[wid][f * 16 + lg * 4 + r][j * 16 + lr] = f2bf(p);
          s += p;
        }
        #pragma unroll
        for (int m = 1; m < 16; m <<= 1) s += __shfl_xor(s, m);
        lrow[f][r] = lrow[f][r] * sc + s;
        oacc[f][0][r] *= sc; oacc[f][1][r] *= sc;
        oacc[f][2][r] *= sc; oacc[f][3][r] *= sc;
      }
    }
    // ---- prefetch next K tile: in flight during PV ----
    if (kt < 8) {
      #pragma unroll
      for (int j = 0; j < 4; j++) {
        const u16* kr = kb + (size_t)(s0 + 64 + j * 16 + lr) * EDIM + lg * 8;
        kf[j][0] = *(const bf16x8*)kr;
        kf[j][1] = *(const bf16x8*)(kr + 32);
      }
    }
    // ---- PV ----
    #pragma unroll
    for (int f = 0; f < 3; f++)
      #pragma unroll
      for (int ks = 0; ks < 2; ks++) {
        bf16x8 pa = *(const bf16x8*)&p_lds[wid][f * 16 + lr][ks * 32 + lg * 8];
        #pragma unroll
        for (int et = 0; et < 4; et++)
          oacc[f][et] = __builtin_amdgcn_mfma_f32_16x16x32_bf16(pa, vf[ks][et], oacc[f][et], 0, 0, 0);
      }
  }
  // ---- epilogue ----
  u16* ob = o + ((size_t)n * SDIM + qbase) * CDIM + h * EDIM;
  #pragma unroll
  for (int f = 0; f < 3; f++)
    #pragma unroll
    for (int r = 0; r < 4; r++) {
      float inv = 1.0f / lrow[f][r];
      #pragma unroll
      for (int et = 0; et < 4; et++)
        ob[(size_t)(f * 16 + lg * 4 + r) * CDIM + et * 16 + lr] = f2bf(oacc[f][et][r] * inv);
    }
}

// ---------------- out projection + skip: out = o @ wo^T + x ----------------
__global__ __launch_bounds__(256) void gemm_proj(const u16* __restrict__ o,
                                                 const u16* __restrict__ wo,
                                                 const float* __restrict__ x,
                                                 float* __restrict__ out) {
  __shared__ u16 ldsA[128 * LDST];
  __shared__ u16 ldsB[128 * LDST];
  f32x4 acc[4][4] = {};
  int tid = threadIdx.x;
  int m0 = blockIdx.y * 128, n0 = blockIdx.x * 128;
  gemm_bt_core(o, wo, CDIM, m0, n0, tid, ldsA, ldsB, acc);
  int lane = tid & 63, wid = tid >> 6;
  int wm = (wid >> 1) * 64, wn = (wid & 1) * 64;
  int lr = lane & 15, rb = (lane >> 4) * 4;
  #pragma unroll
  for (int i = 0; i < 4; i++)
    #pragma unroll
    for (int j = 0; j < 4; j++)
      #pragma unroll
      for (int r = 0; r < 4; r++) {
        int m = m0 + wm + i * 16 + rb + r;
        int jj = n0 + wn + j * 16 + lr;
        int nidx = m / SDIM, hw = m % SDIM;
        int b = nidx >> 3, t = nidx & 7;
        size_t oi = ((size_t)(b * CDIM + jj) * TDIM + t) * SDIM + hw;
        out[oi] = acc[i][j][r] + x[oi];
      }
}

extern "C" void kernel_launch(void* const* d_in, const int* in_sizes, int n_in,
                              void* d_out, int out_size, void* d_ws, size_t ws_size,
                              hipStream_t stream) {
  const float* x      = (const float*)d_in[0];
  const float* pos    = (const float*)d_in[1];
  const float* cond   = (const float*)d_in[2];
  const float* norm_w = (const float*)d_in[3];
  const float* qkv_w  = (const float*)d_in[4];
  const float* scale  = (const float*)d_in[5];
  const float* out_w  = (const float*)d_in[6];
  const float* freqs  = (const float*)d_in[7];
  float* out = (float*)d_out;

  char* ws = (char*)d_ws;
  size_t off = 0;
  auto alloc = [&](size_t bytes) -> char* {
    char* p = ws + off;
    off = (off + bytes + 255) & ~(size_t)255;
    return p;
  };
  float* cs  = (float*)alloc(2 * CDIM * sizeof(float));
  u16* wq    = (u16*)alloc((size_t)QKVN * CDIM * 2);
  u16* wo    = (u16*)alloc((size_t)CDIM * CDIM * 2);
  u16* xn    = (u16*)alloc((size_t)MDIM * CDIM * 2);
  u16* qb    = (u16*)alloc((size_t)MDIM * CDIM * 2);
  u16* kb    = (u16*)alloc((size_t)MDIM * CDIM * 2);
  u16* vt    = (u16*)alloc((size_t)MDIM * CDIM * 2);
  u16* ob    = (u16*)alloc((size_t)MDIM * CDIM * 2);

  convert_kernel<<<dim3((QKVN * CDIM / 4 + 255) / 256), dim3(256), 0, stream>>>(qkv_w, wq, QKVN * CDIM / 4);
  convert_kernel<<<dim3((CDIM * CDIM / 4 + 255) / 256), dim3(256), 0, stream>>>(out_w, wo, CDIM * CDIM / 4);
  cs_kernel<<<dim3(6), dim3(256), 0, stream>>>(cond, norm_w, cs);
  norm_kernel<<<dim3(SDIM / 16, NROW), dim3(16, 16), 0, stream>>>(x, cs, xn);
  gemm_qkv<<<dim3(QKVN / 128, MDIM / 128), dim3(256), 0, stream>>>(xn, wq, qb, kb, vt);
  rope_kernel<<<dim3(NROW * NHEAD * SDIM / 4), dim3(64, 4), 0, stream>>>(qb, kb, pos, freqs, scale);
  attn_mfma<<<dim3(3, NROW * NHEAD), dim3(256), 0, stream>>>(qb, kb, vt, ob);
  gemm_proj<<<dim3(CDIM / 128, MDIM / 128), dim3(256), 0, stream>>>(ob, wo, x, out);
}

// Round 4
// 294.686 us; speedup vs baseline: 6.8558x; 1.1435x over previous
//
#include <hip/hip_runtime.h>
#include <hip/hip_bf16.h>

// ---- geometry (fixed by the problem) ----
// B=2, C=768, T=8, H=24, W=24, nh=12, e=64, n=16, s=576, M=n*s=9216
#define CDIM 768
#define NHEAD 12
#define EDIM 64
#define TDIM 8
#define SDIM 576
#define NROW 16          // B*T
#define MDIM 9216        // NROW*SDIM
#define QKVN 2304

typedef __attribute__((ext_vector_type(4))) float f32x4;
typedef __bf16 bf16x8 __attribute__((ext_vector_type(8)));
typedef unsigned short u16;
typedef __attribute__((ext_vector_type(8))) unsigned short u16x8;

__device__ inline float bf2f(u16 u) {
  union { unsigned int i; float f; } x; x.i = ((unsigned int)u) << 16; return x.f;
}
__device__ inline u16 f2bf(float f) {
  union { float f; unsigned int i; } x; x.f = f;
  unsigned int i = x.i;
  return (u16)((i + 0x7FFFu + ((i >> 16) & 1u)) >> 16);
}
__device__ inline unsigned cvt_pk_bf16(float lo, float hi) {
  unsigned r;
  asm("v_cvt_pk_bf16_f32 %0, %1, %2" : "=v"(r) : "v"(lo), "v"(hi));
  return r;
}

// ---------------- cs = cond @ norm_w^T + 1  (2 x 768) ----------------
__global__ __launch_bounds__(256) void cs_kernel(const float* __restrict__ cond,
                                                 const float* __restrict__ nw,
                                                 float* __restrict__ cs) {
  int idx = blockIdx.x * 256 + threadIdx.x;      // 0..1535
  int b = idx / CDIM, c = idx % CDIM;
  const float* cr = cond + (size_t)b * CDIM;
  const float* wr = nw + (size_t)c * CDIM;
  float s = 1.0f;
  for (int j = 0; j < CDIM; j += 4) {
    float4 a = *(const float4*)(cr + j);
    float4 w = *(const float4*)(wr + j);
    s = fmaf(a.x, w.x, s); s = fmaf(a.y, w.y, s);
    s = fmaf(a.z, w.z, s); s = fmaf(a.w, w.w, s);
  }
  cs[idx] = s;
}

// ---------------- RMS-norm * cs -> xn (M, C) bf16, one-pass via LDS ----------------
__global__ __launch_bounds__(256) void norm_kernel(const float* __restrict__ x,
                                                   const float* __restrict__ cs,
                                                   u16* __restrict__ xn) {
  __shared__ float xs[16][772];
  __shared__ float red[16][17];
  __shared__ float rfac[16];
  int n = blockIdx.y;
  int hw0 = blockIdx.x * 16;
  int b = n >> 3, t = n & 7;
  int tx = threadIdx.x, ty = threadIdx.y;
  const float* xb = x + ((size_t)b * CDIM * TDIM + t) * SDIM;
  float acc = 0.0f;
  for (int c = ty; c < CDIM; c += 16) {
    float v = xb[(size_t)c * (TDIM * SDIM) + hw0 + tx];
    xs[tx][c] = v;
    acc = fmaf(v, v, acc);
  }
  red[ty][tx] = acc;
  __syncthreads();
  if (ty == 0) {
    float s = 0.0f;
    #pragma unroll
    for (int j = 0; j < 16; j++) s += red[j][tx];
    rfac[tx] = rsqrtf(s * (1.0f / (float)CDIM) + 1e-6f);
  }
  __syncthreads();
  const float* csb = cs + (size_t)b * CDIM;
  int flat = ty * 16 + tx;
  #pragma unroll
  for (int i = 0; i < 6; i++) {
    int idx = i * 256 + flat;
    int row = idx / 96;
    int cseg = idx - row * 96;
    int c0 = cseg * 8;
    float rf = rfac[row];
    float4 a0 = *(const float4*)&xs[row][c0];
    float4 a1 = *(const float4*)&xs[row][c0 + 4];
    float4 w0 = *(const float4*)(csb + c0);
    float4 w1 = *(const float4*)(csb + c0 + 4);
    u16x8 ov;
    ov[0] = f2bf(a0.x * w0.x * rf); ov[1] = f2bf(a0.y * w0.y * rf);
    ov[2] = f2bf(a0.z * w0.z * rf); ov[3] = f2bf(a0.w * w0.w * rf);
    ov[4] = f2bf(a1.x * w1.x * rf); ov[5] = f2bf(a1.y * w1.y * rf);
    ov[6] = f2bf(a1.z * w1.z * rf); ov[7] = f2bf(a1.w * w1.w * rf);
    *(u16x8*)(xn + ((size_t)n * SDIM + hw0 + row) * CDIM + c0) = ov;
  }
}

// ---------------- f32 -> bf16 weight convert ----------------
__global__ __launch_bounds__(256) void convert_kernel(const float* __restrict__ src,
                                                      u16* __restrict__ dst, int count4) {
  int i = blockIdx.x * 256 + threadIdx.x;
  if (i < count4) {
    float4 v = *(const float4*)(src + (size_t)i * 4);
    u16* d = dst + (size_t)i * 4;
    d[0] = f2bf(v.x); d[1] = f2bf(v.y); d[2] = f2bf(v.z); d[3] = f2bf(v.w);
  }
}

// ---------------- shared MFMA GEMM core: C = A(M,K) * B(N,K)^T ----------------
#define LDST 56

__device__ __forceinline__ void gemm_bt_core(const u16* __restrict__ A,
                                             const u16* __restrict__ B,
                                             int K, int m0, int n0, int tid,
                                             u16* ldsA, u16* ldsB,
                                             f32x4 acc[4][4]) {
  int lane = tid & 63;
  int wid = tid >> 6;
  int wm = (wid >> 1) * 64, wn = (wid & 1) * 64;
  int lr = lane & 15, lk = (lane >> 4) * 8;
  for (int k0 = 0; k0 < K; k0 += 32) {
    #pragma unroll
    for (int i = tid; i < 512; i += 256) {
      int row = i >> 2, seg = i & 3;
      *(int4*)&ldsA[row * LDST + seg * 8] = *(const int4*)(A + (size_t)(m0 + row) * K + k0 + seg * 8);
      *(int4*)&ldsB[row * LDST + seg * 8] = *(const int4*)(B + (size_t)(n0 + row) * K + k0 + seg * 8);
    }
    __syncthreads();
    bf16x8 af[4], bfr[4];
    #pragma unroll
    for (int i = 0; i < 4; i++) af[i]  = *(const bf16x8*)&ldsA[(wm + i * 16 + lr) * LDST + lk];
    #pragma unroll
    for (int j = 0; j < 4; j++) bfr[j] = *(const bf16x8*)&ldsB[(wn + j * 16 + lr) * LDST + lk];
    #pragma unroll
    for (int i = 0; i < 4; i++)
      #pragma unroll
      for (int j = 0; j < 4; j++)
        acc[i][j] = __builtin_amdgcn_mfma_f32_16x16x32_bf16(af[i], bfr[j], acc[i][j], 0, 0, 0);
    __syncthreads();
  }
}

// ---------------- QKV GEMM with scatter epilogue ----------------
__global__ __launch_bounds__(256) void gemm_qkv(const u16* __restrict__ xn,
                                                const u16* __restrict__ wq,
                                                u16* __restrict__ q,
                                                u16* __restrict__ k,
                                                u16* __restrict__ vt) {
  __shared__ u16 ldsA[128 * LDST];
  __shared__ u16 ldsB[128 * LDST];
  f32x4 acc[4][4] = {};
  int tid = threadIdx.x;
  int m0 = blockIdx.y * 128, n0 = blockIdx.x * 128;
  gemm_bt_core(xn, wq, CDIM, m0, n0, tid, ldsA, ldsB, acc);
  int lane = tid & 63, wid = tid >> 6;
  int wm = (wid >> 1) * 64, wn = (wid & 1) * 64;
  int lr = lane & 15, rb = (lane >> 4) * 4;
  int part = n0 / CDIM;
  #pragma unroll
  for (int i = 0; i < 4; i++)
    #pragma unroll
    for (int j = 0; j < 4; j++)
      #pragma unroll
      for (int r = 0; r < 4; r++) {
        int m = m0 + wm + i * 16 + rb + r;
        int jj = n0 + wn + j * 16 + lr;
        int nidx = m / SDIM, hw = m % SDIM;
        int rem = jj - part * CDIM;
        int h = rem >> 6, e = rem & 63;
        u16 val = f2bf(acc[i][j][r]);
        if (part == 0)      q[((size_t)(nidx * NHEAD + h) * SDIM + hw) * EDIM + e] = val;
        else if (part == 1) k[((size_t)(nidx * NHEAD + h) * SDIM + hw) * EDIM + e] = val;
        else                vt[((size_t)(nidx * NHEAD + h) * EDIM + e) * SDIM + hw] = val;
      }
}

// ---------------- cosine-norm + RoPE on q,k in place ----------------
// q additionally scaled by log2(e) so attention can use exp2 directly.
__global__ __launch_bounds__(256) void rope_kernel(u16* __restrict__ q, u16* __restrict__ k,
                                                   const float* __restrict__ pos,
                                                   const float* __restrict__ freqs,
                                                   const float* __restrict__ scale) {
  int row = blockIdx.x * 4 + threadIdx.y;   // (n*12+h)*576 + s
  int e = threadIdx.x;
  int sp = row % SDIM;
  int nh_ = row / SDIM;
  int h = nh_ % NHEAD;
  int n = nh_ / NHEAD;
  int b = n >> 3;
  float p0 = pos[((size_t)b * SDIM + sp) * 2 + 0];
  float p1 = pos[((size_t)b * SDIM + sp) * 2 + 1];
  float cth = 1.0f, sth = 0.0f;
  if (e < 32) {
    int jj = e & 15;
    float th = (jj < 8) ? p0 * freqs[h * 8 + jj] : p1 * freqs[h * 8 + jj - 8];
    cth = cosf(th); sth = sinf(th);
  }
  float sqb = sqrtf(scale[h]);
  #pragma unroll
  for (int pass = 0; pass < 2; pass++) {
    float sq = pass ? sqb : sqb * 1.44269504f;   // fold log2(e) into q
    u16* base = (pass ? k : q) + (size_t)row * EDIM;
    float v = bf2f(base[e]);
    float ss = v * v;
    #pragma unroll
    for (int m = 1; m < 64; m <<= 1) ss += __shfl_xor(ss, m);
    float qn = v * (sq * rsqrtf(ss + 1e-6f));
    float pr = __shfl_xor(qn, 16);
    float outv;
    if (e < 16)      outv = qn * cth - pr * sth;
    else if (e < 32) outv = qn * cth + pr * sth;
    else             outv = qn;
    base[e] = f2bf(outv);
  }
}

// ---------------- MFMA flash attention v3 ----------------
// Logits bounded (|q.k| <= 10 after cosine-norm * sqrt(10)): NO max tracking,
// p = exp2(s) directly (log2e pre-folded into q). Swapped QK^T mfma(K,Q):
// each lane owns q-row lr -> pack P via v_cvt_pk_bf16_f32 + ds_write_b32,
// row-sum is lane-local (one cross-lane reduce at the very end).
// Single-wave blocks, 48 q-rows each: grid 2304 = 8 XCD x 288, chunk-swizzled.
__global__ __launch_bounds__(64, 2) void attn_mfma(const u16* __restrict__ q,
                                                   const u16* __restrict__ k,
                                                   const u16* __restrict__ vt,
                                                   u16* __restrict__ o) {
  __shared__ u16 p_lds[48][72];
  int L = blockIdx.x;
  int cid = (L & 7) * 288 + (L >> 3);            // XCD-chunked bijective remap
  int nh_ = cid / 12;
  int qt = cid - nh_ * 12;
  int n = nh_ / NHEAD, h = nh_ - n * NHEAD;
  int lane = threadIdx.x;
  int lr = lane & 15, lg = lane >> 4;
  int qbase = qt * 48;

  const u16* qp = q + ((size_t)nh_ * SDIM + qbase) * EDIM;
  bf16x8 qa[3][2];
  #pragma unroll
  for (int f = 0; f < 3; f++) {
    qa[f][0] = *(const bf16x8*)(qp + (size_t)(f * 16 + lr) * EDIM + lg * 8);
    qa[f][1] = *(const bf16x8*)(qp + (size_t)(f * 16 + lr) * EDIM + 32 + lg * 8);
  }
  const u16* kb = k + (size_t)nh_ * SDIM * EDIM;
  const u16* vb = vt + (size_t)nh_ * EDIM * SDIM;

  float psum[3] = {0.0f, 0.0f, 0.0f};
  f32x4 oacc[3][4] = {};

  bf16x8 kf[4][2];
  #pragma unroll
  for (int j = 0; j < 4; j++) {
    const u16* kr = kb + (size_t)(j * 16 + lr) * EDIM + lg * 8;
    kf[j][0] = *(const bf16x8*)kr;
    kf[j][1] = *(const bf16x8*)(kr + 32);
  }

  #pragma unroll 1
  for (int kt = 0; kt < 9; kt++) {
    int s0 = kt * 64;
    // ---- V loads: in flight during QK^T + exp ----
    bf16x8 vf[2][4];
    #pragma unroll
    for (int ks = 0; ks < 2; ks++)
      #pragma unroll
      for (int et = 0; et < 4; et++)
        vf[ks][et] = *(const bf16x8*)(vb + (size_t)(et * 16 + lr) * SDIM + s0 + ks * 32 + lg * 8);
    // ---- swapped QK^T: S^T[kcol][qrow], lane owns qrow=lr, kcols j*16+lg*4+r ----
    #pragma unroll
    for (int f = 0; f < 3; f++) {
      f32x4 sfr[4] = {};
      #pragma unroll
      for (int j = 0; j < 4; j++) {
        sfr[j] = __builtin_amdgcn_mfma_f32_16x16x32_bf16(kf[j][0], qa[f][0], sfr[j], 0, 0, 0);
        sfr[j] = __builtin_amdgcn_mfma_f32_16x16x32_bf16(kf[j][1], qa[f][1], sfr[j], 0, 0, 0);
      }
      float fs = 0.0f;
      #pragma unroll
      for (int j = 0; j < 4; j++) {
        float p0 = exp2f(sfr[j][0]);
        float p1 = exp2f(sfr[j][1]);
        float p2 = exp2f(sfr[j][2]);
        float p3 = exp2f(sfr[j][3]);
        unsigned w0 = cvt_pk_bf16(p0, p1);
        unsigned w1 = cvt_pk_bf16(p2, p3);
        *(unsigned*)&p_lds[f * 16 + lr][j * 16 + lg * 4]     = w0;
        *(unsigned*)&p_lds[f * 16 + lr][j * 16 + lg * 4 + 2] = w1;
        fs += (p0 + p1) + (p2 + p3);
      }
      psum[f] += fs;
    }
    // ---- prefetch next K tile: in flight during PV ----
    if (kt < 8) {
      #pragma unroll
      for (int j = 0; j < 4; j++) {
        const u16* kr = kb + (size_t)(s0 + 64 + j * 16 + lr) * EDIM + lg * 8;
        kf[j][0] = *(const bf16x8*)kr;
        kf[j][1] = *(const bf16x8*)(kr + 32);
      }
    }
    // ---- PV: O += P(48x64) @ V(64x64) ----
    #pragma unroll
    for (int f = 0; f < 3; f++)
      #pragma unroll
      for (int ks = 0; ks < 2; ks++) {
        bf16x8 pa = *(const bf16x8*)&p_lds[f * 16 + lr][ks * 32 + lg * 8];
        #pragma unroll
        for (int et = 0; et < 4; et++)
          oacc[f][et] = __builtin_amdgcn_mfma_f32_16x16x32_bf16(pa, vf[ks][et], oacc[f][et], 0, 0, 0);
      }
  }
  // ---- epilogue: one reduce per frag, distribute inv, store ----
  u16* ob = o + ((size_t)n * SDIM + qbase) * CDIM + h * EDIM;
  #pragma unroll
  for (int f = 0; f < 3; f++) {
    float s = psum[f];
    s += __shfl_xor(s, 16);
    s += __shfl_xor(s, 32);
    float inv = 1.0f / s;                        // valid for q-row = lr
    #pragma unroll
    for (int r = 0; r < 4; r++) {
      float invr = __shfl(inv, lg * 4 + r);      // inv for q-row = lg*4+r
      #pragma unroll
      for (int et = 0; et < 4; et++)
        ob[(size_t)(f * 16 + lg * 4 + r) * CDIM + et * 16 + lr] = f2bf(oacc[f][et][r] * invr);
    }
  }
}

// ---------------- out projection + skip: out = o @ wo^T + x ----------------
__global__ __launch_bounds__(256) void gemm_proj(const u16* __restrict__ o,
                                                 const u16* __restrict__ wo,
                                                 const float* __restrict__ x,
                                                 float* __restrict__ out) {
  __shared__ u16 ldsA[128 * LDST];
  __shared__ u16 ldsB[128 * LDST];
  f32x4 acc[4][4] = {};
  int tid = threadIdx.x;
  int m0 = blockIdx.y * 128, n0 = blockIdx.x * 128;
  gemm_bt_core(o, wo, CDIM, m0, n0, tid, ldsA, ldsB, acc);
  int lane = tid & 63, wid = tid >> 6;
  int wm = (wid >> 1) * 64, wn = (wid & 1) * 64;
  int lr = lane & 15, rb = (lane >> 4) * 4;
  #pragma unroll
  for (int i = 0; i < 4; i++)
    #pragma unroll
    for (int j = 0; j < 4; j++)
      #pragma unroll
      for (int r = 0; r < 4; r++) {
        int m = m0 + wm + i * 16 + rb + r;
        int jj = n0 + wn + j * 16 + lr;
        int nidx = m / SDIM, hw = m % SDIM;
        int b = nidx >> 3, t = nidx & 7;
        size_t oi = ((size_t)(b * CDIM + jj) * TDIM + t) * SDIM + hw;
        out[oi] = acc[i][j][r] + x[oi];
      }
}

extern "C" void kernel_launch(void* const* d_in, const int* in_sizes, int n_in,
                              void* d_out, int out_size, void* d_ws, size_t ws_size,
                              hipStream_t stream) {
  const float* x      = (const float*)d_in[0];
  const float* pos    = (const float*)d_in[1];
  const float* cond   = (const float*)d_in[2];
  const float* norm_w = (const float*)d_in[3];
  const float* qkv_w  = (const float*)d_in[4];
  const float* scale  = (const float*)d_in[5];
  const float* out_w  = (const float*)d_in[6];
  const float* freqs  = (const float*)d_in[7];
  float* out = (float*)d_out;

  char* ws = (char*)d_ws;
  size_t off = 0;
  auto alloc = [&](size_t bytes) -> char* {
    char* p = ws + off;
    off = (off + bytes + 255) & ~(size_t)255;
    return p;
  };
  float* cs  = (float*)alloc(2 * CDIM * sizeof(float));
  u16* wq    = (u16*)alloc((size_t)QKVN * CDIM * 2);
  u16* wo    = (u16*)alloc((size_t)CDIM * CDIM * 2);
  u16* xn    = (u16*)alloc((size_t)MDIM * CDIM * 2);
  u16* qb    = (u16*)alloc((size_t)MDIM * CDIM * 2);
  u16* kb    = (u16*)alloc((size_t)MDIM * CDIM * 2);
  u16* vt    = (u16*)alloc((size_t)MDIM * CDIM * 2);
  u16* ob    = (u16*)alloc((size_t)MDIM * CDIM * 2);

  convert_kernel<<<dim3((QKVN * CDIM / 4 + 255) / 256), dim3(256), 0, stream>>>(qkv_w, wq, QKVN * CDIM / 4);
  convert_kernel<<<dim3((CDIM * CDIM / 4 + 255) / 256), dim3(256), 0, stream>>>(out_w, wo, CDIM * CDIM / 4);
  cs_kernel<<<dim3(6), dim3(256), 0, stream>>>(cond, norm_w, cs);
  norm_kernel<<<dim3(SDIM / 16, NROW), dim3(16, 16), 0, stream>>>(x, cs, xn);
  gemm_qkv<<<dim3(QKVN / 128, MDIM / 128), dim3(256), 0, stream>>>(xn, wq, qb, kb, vt);
  rope_kernel<<<dim3(NROW * NHEAD * SDIM / 4), dim3(64, 4), 0, stream>>>(qb, kb, pos, freqs, scale);
  attn_mfma<<<dim3(2304), dim3(64), 0, stream>>>(qb, kb, vt, ob);
  gemm_proj<<<dim3(CDIM / 128, MDIM / 128), dim3(256), 0, stream>>>(ob, wo, x, out);
}

// Round 5
// 267.157 us; speedup vs baseline: 7.5622x; 1.1030x over previous
//
#include <hip/hip_runtime.h>
#include <hip/hip_bf16.h>

// ---- geometry (fixed by the problem) ----
// B=2, C=768, T=8, H=24, W=24, nh=12, e=64, n=16, s=576, M=n*s=9216
#define CDIM 768
#define NHEAD 12
#define EDIM 64
#define TDIM 8
#define SDIM 576
#define NROW 16          // B*T
#define MDIM 9216        // NROW*SDIM
#define QKVN 2304

typedef __attribute__((ext_vector_type(4))) float f32x4;
typedef __bf16 bf16x8 __attribute__((ext_vector_type(8)));
typedef unsigned short u16;
typedef __attribute__((ext_vector_type(8))) unsigned short u16x8;

__device__ inline float bf2f(u16 u) {
  union { unsigned int i; float f; } x; x.i = ((unsigned int)u) << 16; return x.f;
}
__device__ inline u16 f2bf(float f) {
  union { float f; unsigned int i; } x; x.f = f;
  unsigned int i = x.i;
  return (u16)((i + 0x7FFFu + ((i >> 16) & 1u)) >> 16);
}
__device__ inline unsigned cvt_pk_bf16(float lo, float hi) {
  unsigned r;
  asm("v_cvt_pk_bf16_f32 %0, %1, %2" : "=v"(r) : "v"(lo), "v"(hi));
  return r;
}

// ---------------- cs = cond @ norm_w^T + 1  (2 x 768) ----------------
__global__ __launch_bounds__(256) void cs_kernel(const float* __restrict__ cond,
                                                 const float* __restrict__ nw,
                                                 float* __restrict__ cs) {
  int idx = blockIdx.x * 256 + threadIdx.x;      // 0..1535
  int b = idx / CDIM, c = idx % CDIM;
  const float* cr = cond + (size_t)b * CDIM;
  const float* wr = nw + (size_t)c * CDIM;
  float s = 1.0f;
  for (int j = 0; j < CDIM; j += 4) {
    float4 a = *(const float4*)(cr + j);
    float4 w = *(const float4*)(wr + j);
    s = fmaf(a.x, w.x, s); s = fmaf(a.y, w.y, s);
    s = fmaf(a.z, w.z, s); s = fmaf(a.w, w.w, s);
  }
  cs[idx] = s;
}

// ---------------- RMS-norm * cs -> xn (M, C) bf16, one-pass via LDS ----------------
__global__ __launch_bounds__(256) void norm_kernel(const float* __restrict__ x,
                                                   const float* __restrict__ cs,
                                                   u16* __restrict__ xn) {
  __shared__ float xs[16][772];
  __shared__ float red[16][17];
  __shared__ float rfac[16];
  int n = blockIdx.y;
  int hw0 = blockIdx.x * 16;
  int b = n >> 3, t = n & 7;
  int tx = threadIdx.x, ty = threadIdx.y;
  const float* xb = x + ((size_t)b * CDIM * TDIM + t) * SDIM;
  float acc = 0.0f;
  for (int c = ty; c < CDIM; c += 16) {
    float v = xb[(size_t)c * (TDIM * SDIM) + hw0 + tx];
    xs[tx][c] = v;
    acc = fmaf(v, v, acc);
  }
  red[ty][tx] = acc;
  __syncthreads();
  if (ty == 0) {
    float s = 0.0f;
    #pragma unroll
    for (int j = 0; j < 16; j++) s += red[j][tx];
    rfac[tx] = rsqrtf(s * (1.0f / (float)CDIM) + 1e-6f);
  }
  __syncthreads();
  const float* csb = cs + (size_t)b * CDIM;
  int flat = ty * 16 + tx;
  #pragma unroll
  for (int i = 0; i < 6; i++) {
    int idx = i * 256 + flat;
    int row = idx / 96;
    int cseg = idx - row * 96;
    int c0 = cseg * 8;
    float rf = rfac[row];
    float4 a0 = *(const float4*)&xs[row][c0];
    float4 a1 = *(const float4*)&xs[row][c0 + 4];
    float4 w0 = *(const float4*)(csb + c0);
    float4 w1 = *(const float4*)(csb + c0 + 4);
    u16x8 ov;
    ov[0] = f2bf(a0.x * w0.x * rf); ov[1] = f2bf(a0.y * w0.y * rf);
    ov[2] = f2bf(a0.z * w0.z * rf); ov[3] = f2bf(a0.w * w0.w * rf);
    ov[4] = f2bf(a1.x * w1.x * rf); ov[5] = f2bf(a1.y * w1.y * rf);
    ov[6] = f2bf(a1.z * w1.z * rf); ov[7] = f2bf(a1.w * w1.w * rf);
    *(u16x8*)(xn + ((size_t)n * SDIM + hw0 + row) * CDIM + c0) = ov;
  }
}

// ---------------- f32 -> bf16 weight convert ----------------
__global__ __launch_bounds__(256) void convert_kernel(const float* __restrict__ src,
                                                      u16* __restrict__ dst, int count4) {
  int i = blockIdx.x * 256 + threadIdx.x;
  if (i < count4) {
    float4 v = *(const float4*)(src + (size_t)i * 4);
    u16* d = dst + (size_t)i * 4;
    d[0] = f2bf(v.x); d[1] = f2bf(v.y); d[2] = f2bf(v.z); d[3] = f2bf(v.w);
  }
}

// ---------------- m97-style MFMA GEMM core: C = A(M,K) * B(N,K)^T ----------------
// 128x128 tile, BK=32, 4 waves 2x2. Staging via global_load_lds width=16 into
// LINEAR LDS [128][32] (wave-uniform base + lane*16 — layout must be linear).
// 2 barriers per k-step (m97 structure, 874 TF verified on 4096^3).
__device__ __forceinline__ void gemm_bt_lds(const u16* __restrict__ A,
                                            const u16* __restrict__ B,
                                            int K, int m0, int n0, int tid,
                                            u16* ldsA, u16* ldsB,
                                            f32x4 acc[4][4]) {
  int lane = tid & 63;
  int wid = tid >> 6;
  int wm = (wid >> 1) * 64, wn = (wid & 1) * 64;
  int lr = lane & 15, lg = lane >> 4;
  // staging: wave w covers rows [w*32, w*32+32) in 2 issues of 16 rows;
  // lane l -> row base + (l>>2), k-seg (l&3)*8 elems (16 B)
  const u16* gA = A + (size_t)(m0 + wid * 32 + (lane >> 2)) * K + (lane & 3) * 8;
  const u16* gB = B + (size_t)(n0 + wid * 32 + (lane >> 2)) * K + (lane & 3) * 8;
  u16* dA = ldsA + wid * 32 * 32;
  u16* dB = ldsB + wid * 32 * 32;
  for (int k0 = 0; k0 < K; k0 += 32) {
    __syncthreads();                       // prev reads done before overwrite
    #pragma unroll
    for (int is = 0; is < 2; is++) {
      __builtin_amdgcn_global_load_lds(
          (const __attribute__((address_space(1))) unsigned int*)(gA + (size_t)(is * 16) * K + k0),
          (__attribute__((address_space(3))) unsigned int*)(dA + is * 512),
          16, 0, 0);
      __builtin_amdgcn_global_load_lds(
          (const __attribute__((address_space(1))) unsigned int*)(gB + (size_t)(is * 16) * K + k0),
          (__attribute__((address_space(3))) unsigned int*)(dB + is * 512),
          16, 0, 0);
    }
    __syncthreads();                       // implies vmcnt(0) drain: loads visible
    bf16x8 af[4], bfr[4];
    #pragma unroll
    for (int i = 0; i < 4; i++) af[i]  = *(const bf16x8*)&ldsA[(wm + i * 16 + lr) * 32 + lg * 8];
    #pragma unroll
    for (int j = 0; j < 4; j++) bfr[j] = *(const bf16x8*)&ldsB[(wn + j * 16 + lr) * 32 + lg * 8];
    #pragma unroll
    for (int i = 0; i < 4; i++)
      #pragma unroll
      for (int j = 0; j < 4; j++)
        acc[i][j] = __builtin_amdgcn_mfma_f32_16x16x32_bf16(af[i], bfr[j], acc[i][j], 0, 0, 0);
  }
}

// XCD-chunk swizzle: grid = 8 XCD * 9 m-blocks * NBLK n-blocks (bijective).
// Each XCD owns one contiguous 9-block A-stripe (1.8 MB) and sweeps n with it
// L2-resident; working set per XCD ~2.2 MB < 4 MB L2.
__device__ __forceinline__ void swz_tile(int L, int& m0, int& n0) {
  int xcd = L & 7, loc = L >> 3;
  int nblk = loc / 9, mloc = loc - nblk * 9;
  m0 = (xcd * 9 + mloc) * 128;
  n0 = nblk * 128;
}

// ---------------- QKV GEMM with scatter epilogue ----------------
__global__ __launch_bounds__(256) void gemm_qkv(const u16* __restrict__ xn,
                                                const u16* __restrict__ wq,
                                                u16* __restrict__ q,
                                                u16* __restrict__ k,
                                                u16* __restrict__ vt) {
  __shared__ u16 ldsA[128 * 32];
  __shared__ u16 ldsB[128 * 32];
  f32x4 acc[4][4] = {};
  int tid = threadIdx.x;
  int m0, n0;
  swz_tile(blockIdx.x, m0, n0);
  gemm_bt_lds(xn, wq, CDIM, m0, n0, tid, ldsA, ldsB, acc);
  int lane = tid & 63, wid = tid >> 6;
  int wm = (wid >> 1) * 64, wn = (wid & 1) * 64;
  int lr = lane & 15, rb = (lane >> 4) * 4;
  int part = n0 / CDIM;
  #pragma unroll
  for (int i = 0; i < 4; i++)
    #pragma unroll
    for (int j = 0; j < 4; j++)
      #pragma unroll
      for (int r = 0; r < 4; r++) {
        int m = m0 + wm + i * 16 + rb + r;
        int jj = n0 + wn + j * 16 + lr;
        int nidx = m / SDIM, hw = m % SDIM;
        int rem = jj - part * CDIM;
        int h = rem >> 6, e = rem & 63;
        u16 val = f2bf(acc[i][j][r]);
        if (part == 0)      q[((size_t)(nidx * NHEAD + h) * SDIM + hw) * EDIM + e] = val;
        else if (part == 1) k[((size_t)(nidx * NHEAD + h) * SDIM + hw) * EDIM + e] = val;
        else                vt[((size_t)(nidx * NHEAD + h) * EDIM + e) * SDIM + hw] = val;
      }
}

// ---------------- cosine-norm + RoPE on q,k in place ----------------
// q additionally scaled by log2(e) so attention can use exp2 directly.
__global__ __launch_bounds__(256) void rope_kernel(u16* __restrict__ q, u16* __restrict__ k,
                                                   const float* __restrict__ pos,
                                                   const float* __restrict__ freqs,
                                                   const float* __restrict__ scale) {
  int row = blockIdx.x * 4 + threadIdx.y;   // (n*12+h)*576 + s
  int e = threadIdx.x;
  int sp = row % SDIM;
  int nh_ = row / SDIM;
  int h = nh_ % NHEAD;
  int n = nh_ / NHEAD;
  int b = n >> 3;
  float p0 = pos[((size_t)b * SDIM + sp) * 2 + 0];
  float p1 = pos[((size_t)b * SDIM + sp) * 2 + 1];
  float cth = 1.0f, sth = 0.0f;
  if (e < 32) {
    int jj = e & 15;
    float th = (jj < 8) ? p0 * freqs[h * 8 + jj] : p1 * freqs[h * 8 + jj - 8];
    cth = cosf(th); sth = sinf(th);
  }
  float sqb = sqrtf(scale[h]);
  #pragma unroll
  for (int pass = 0; pass < 2; pass++) {
    float sq = pass ? sqb : sqb * 1.44269504f;   // fold log2(e) into q
    u16* base = (pass ? k : q) + (size_t)row * EDIM;
    float v = bf2f(base[e]);
    float ss = v * v;
    #pragma unroll
    for (int m = 1; m < 64; m <<= 1) ss += __shfl_xor(ss, m);
    float qn = v * (sq * rsqrtf(ss + 1e-6f));
    float pr = __shfl_xor(qn, 16);
    float outv;
    if (e < 16)      outv = qn * cth - pr * sth;
    else if (e < 32) outv = qn * cth + pr * sth;
    else             outv = qn;
    base[e] = f2bf(outv);
  }
}

// ---------------- MFMA flash attention v3 ----------------
// Logits bounded (|q.k| <= 10 after cosine-norm * sqrt(10)): NO max tracking,
// p = exp2(s) directly (log2e pre-folded into q). Swapped QK^T mfma(K,Q):
// each lane owns q-row lr -> pack P via v_cvt_pk_bf16_f32 + ds_write_b32,
// row-sum is lane-local (one cross-lane reduce at the very end).
// Single-wave blocks, 48 q-rows each: grid 2304 = 8 XCD x 288, chunk-swizzled.
__global__ __launch_bounds__(64, 2) void attn_mfma(const u16* __restrict__ q,
                                                   const u16* __restrict__ k,
                                                   const u16* __restrict__ vt,
                                                   u16* __restrict__ o) {
  __shared__ u16 p_lds[48][72];
  int L = blockIdx.x;
  int cid = (L & 7) * 288 + (L >> 3);            // XCD-chunked bijective remap
  int nh_ = cid / 12;
  int qt = cid - nh_ * 12;
  int n = nh_ / NHEAD, h = nh_ - n * NHEAD;
  int lane = threadIdx.x;
  int lr = lane & 15, lg = lane >> 4;
  int qbase = qt * 48;

  const u16* qp = q + ((size_t)nh_ * SDIM + qbase) * EDIM;
  bf16x8 qa[3][2];
  #pragma unroll
  for (int f = 0; f < 3; f++) {
    qa[f][0] = *(const bf16x8*)(qp + (size_t)(f * 16 + lr) * EDIM + lg * 8);
    qa[f][1] = *(const bf16x8*)(qp + (size_t)(f * 16 + lr) * EDIM + 32 + lg * 8);
  }
  const u16* kb = k + (size_t)nh_ * SDIM * EDIM;
  const u16* vb = vt + (size_t)nh_ * EDIM * SDIM;

  float psum[3] = {0.0f, 0.0f, 0.0f};
  f32x4 oacc[3][4] = {};

  bf16x8 kf[4][2];
  #pragma unroll
  for (int j = 0; j < 4; j++) {
    const u16* kr = kb + (size_t)(j * 16 + lr) * EDIM + lg * 8;
    kf[j][0] = *(const bf16x8*)kr;
    kf[j][1] = *(const bf16x8*)(kr + 32);
  }

  #pragma unroll 1
  for (int kt = 0; kt < 9; kt++) {
    int s0 = kt * 64;
    // ---- V loads: in flight during QK^T + exp ----
    bf16x8 vf[2][4];
    #pragma unroll
    for (int ks = 0; ks < 2; ks++)
      #pragma unroll
      for (int et = 0; et < 4; et++)
        vf[ks][et] = *(const bf16x8*)(vb + (size_t)(et * 16 + lr) * SDIM + s0 + ks * 32 + lg * 8);
    // ---- swapped QK^T: S^T[kcol][qrow], lane owns qrow=lr, kcols j*16+lg*4+r ----
    #pragma unroll
    for (int f = 0; f < 3; f++) {
      f32x4 sfr[4] = {};
      #pragma unroll
      for (int j = 0; j < 4; j++) {
        sfr[j] = __builtin_amdgcn_mfma_f32_16x16x32_bf16(kf[j][0], qa[f][0], sfr[j], 0, 0, 0);
        sfr[j] = __builtin_amdgcn_mfma_f32_16x16x32_bf16(kf[j][1], qa[f][1], sfr[j], 0, 0, 0);
      }
      float fs = 0.0f;
      #pragma unroll
      for (int j = 0; j < 4; j++) {
        float p0 = exp2f(sfr[j][0]);
        float p1 = exp2f(sfr[j][1]);
        float p2 = exp2f(sfr[j][2]);
        float p3 = exp2f(sfr[j][3]);
        unsigned w0 = cvt_pk_bf16(p0, p1);
        unsigned w1 = cvt_pk_bf16(p2, p3);
        *(unsigned*)&p_lds[f * 16 + lr][j * 16 + lg * 4]     = w0;
        *(unsigned*)&p_lds[f * 16 + lr][j * 16 + lg * 4 + 2] = w1;
        fs += (p0 + p1) + (p2 + p3);
      }
      psum[f] += fs;
    }
    // ---- prefetch next K tile: in flight during PV ----
    if (kt < 8) {
      #pragma unroll
      for (int j = 0; j < 4; j++) {
        const u16* kr = kb + (size_t)(s0 + 64 + j * 16 + lr) * EDIM + lg * 8;
        kf[j][0] = *(const bf16x8*)kr;
        kf[j][1] = *(const bf16x8*)(kr + 32);
      }
    }
    // ---- PV: O += P(48x64) @ V(64x64) ----
    #pragma unroll
    for (int f = 0; f < 3; f++)
      #pragma unroll
      for (int ks = 0; ks < 2; ks++) {
        bf16x8 pa = *(const bf16x8*)&p_lds[f * 16 + lr][ks * 32 + lg * 8];
        #pragma unroll
        for (int et = 0; et < 4; et++)
          oacc[f][et] = __builtin_amdgcn_mfma_f32_16x16x32_bf16(pa, vf[ks][et], oacc[f][et], 0, 0, 0);
      }
  }
  // ---- epilogue: one reduce per frag, distribute inv, store ----
  u16* ob = o + ((size_t)n * SDIM + qbase) * CDIM + h * EDIM;
  #pragma unroll
  for (int f = 0; f < 3; f++) {
    float s = psum[f];
    s += __shfl_xor(s, 16);
    s += __shfl_xor(s, 32);
    float inv = 1.0f / s;                        // valid for q-row = lr
    #pragma unroll
    for (int r = 0; r < 4; r++) {
      float invr = __shfl(inv, lg * 4 + r);      // inv for q-row = lg*4+r
      #pragma unroll
      for (int et = 0; et < 4; et++)
        ob[(size_t)(f * 16 + lg * 4 + r) * CDIM + et * 16 + lr] = f2bf(oacc[f][et][r] * invr);
    }
  }
}

// ---------------- out projection + skip: out = o @ wo^T + x ----------------
__global__ __launch_bounds__(256) void gemm_proj(const u16* __restrict__ o,
                                                 const u16* __restrict__ wo,
                                                 const float* __restrict__ x,
                                                 float* __restrict__ out) {
  __shared__ u16 ldsA[128 * 32];
  __shared__ u16 ldsB[128 * 32];
  f32x4 acc[4][4] = {};
  int tid = threadIdx.x;
  int m0, n0;
  swz_tile(blockIdx.x, m0, n0);
  gemm_bt_lds(o, wo, CDIM, m0, n0, tid, ldsA, ldsB, acc);
  int lane = tid & 63, wid = tid >> 6;
  int wm = (wid >> 1) * 64, wn = (wid & 1) * 64;
  int lr = lane & 15, rb = (lane >> 4) * 4;
  #pragma unroll
  for (int i = 0; i < 4; i++)
    #pragma unroll
    for (int j = 0; j < 4; j++)
      #pragma unroll
      for (int r = 0; r < 4; r++) {
        int m = m0 + wm + i * 16 + rb + r;
        int jj = n0 + wn + j * 16 + lr;
        int nidx = m / SDIM, hw = m % SDIM;
        int b = nidx >> 3, t = nidx & 7;
        size_t oi = ((size_t)(b * CDIM + jj) * TDIM + t) * SDIM + hw;
        out[oi] = acc[i][j][r] + x[oi];
      }
}

extern "C" void kernel_launch(void* const* d_in, const int* in_sizes, int n_in,
                              void* d_out, int out_size, void* d_ws, size_t ws_size,
                              hipStream_t stream) {
  const float* x      = (const float*)d_in[0];
  const float* pos    = (const float*)d_in[1];
  const float* cond   = (const float*)d_in[2];
  const float* norm_w = (const float*)d_in[3];
  const float* qkv_w  = (const float*)d_in[4];
  const float* scale  = (const float*)d_in[5];
  const float* out_w  = (const float*)d_in[6];
  const float* freqs  = (const float*)d_in[7];
  float* out = (float*)d_out;

  char* ws = (char*)d_ws;
  size_t off = 0;
  auto alloc = [&](size_t bytes) -> char* {
    char* p = ws + off;
    off = (off + bytes + 255) & ~(size_t)255;
    return p;
  };
  float* cs  = (float*)alloc(2 * CDIM * sizeof(float));
  u16* wq    = (u16*)alloc((size_t)QKVN * CDIM * 2);
  u16* wo    = (u16*)alloc((size_t)CDIM * CDIM * 2);
  u16* xn    = (u16*)alloc((size_t)MDIM * CDIM * 2);
  u16* qb    = (u16*)alloc((size_t)MDIM * CDIM * 2);
  u16* kb    = (u16*)alloc((size_t)MDIM * CDIM * 2);
  u16* vt    = (u16*)alloc((size_t)MDIM * CDIM * 2);
  u16* ob    = (u16*)alloc((size_t)MDIM * CDIM * 2);

  convert_kernel<<<dim3((QKVN * CDIM / 4 + 255) / 256), dim3(256), 0, stream>>>(qkv_w, wq, QKVN * CDIM / 4);
  convert_kernel<<<dim3((CDIM * CDIM / 4 + 255) / 256), dim3(256), 0, stream>>>(out_w, wo, CDIM * CDIM / 4);
  cs_kernel<<<dim3(6), dim3(256), 0, stream>>>(cond, norm_w, cs);
  norm_kernel<<<dim3(SDIM / 16, NROW), dim3(16, 16), 0, stream>>>(x, cs, xn);
  gemm_qkv<<<dim3(8 * 9 * (QKVN / 128)), dim3(256), 0, stream>>>(xn, wq, qb, kb, vt);
  rope_kernel<<<dim3(NROW * NHEAD * SDIM / 4), dim3(64, 4), 0, stream>>>(qb, kb, pos, freqs, scale);
  attn_mfma<<<dim3(2304), dim3(64), 0, stream>>>(qb, kb, vt, ob);
  gemm_proj<<<dim3(8 * 9 * (CDIM / 128)), dim3(256), 0, stream>>>(ob, wo, x, out);
}

// Round 6
// 223.577 us; speedup vs baseline: 9.0362x; 1.1949x over previous
//
#include <hip/hip_runtime.h>
#include <hip/hip_bf16.h>

// ---- geometry (fixed by the problem) ----
// B=2, C=768, T=8, H=24, W=24, nh=12, e=64, n=16, s=576, M=n*s=9216
#define CDIM 768
#define NHEAD 12
#define EDIM 64
#define TDIM 8
#define SDIM 576
#define NROW 16          // B*T
#define MDIM 9216        // NROW*SDIM
#define QKVN 2304

typedef __attribute__((ext_vector_type(4))) float f32x4;
typedef __bf16 bf16x8 __attribute__((ext_vector_type(8)));
typedef unsigned short u16;
typedef __attribute__((ext_vector_type(8))) unsigned short u16x8;

__device__ inline float bf2f(u16 u) {
  union { unsigned int i; float f; } x; x.i = ((unsigned int)u) << 16; return x.f;
}
__device__ inline u16 f2bf(float f) {
  union { float f; unsigned int i; } x; x.f = f;
  unsigned int i = x.i;
  return (u16)((i + 0x7FFFu + ((i >> 16) & 1u)) >> 16);
}
__device__ inline unsigned cvt_pk_bf16(float lo, float hi) {
  unsigned r;
  asm("v_cvt_pk_bf16_f32 %0, %1, %2" : "=v"(r) : "v"(lo), "v"(hi));
  return r;
}

// ---------------- cs = cond @ norm_w^T + 1  (2 x 768) ----------------
__global__ __launch_bounds__(256) void cs_kernel(const float* __restrict__ cond,
                                                 const float* __restrict__ nw,
                                                 float* __restrict__ cs) {
  int idx = blockIdx.x * 256 + threadIdx.x;      // 0..1535
  int b = idx / CDIM, c = idx % CDIM;
  const float* cr = cond + (size_t)b * CDIM;
  const float* wr = nw + (size_t)c * CDIM;
  float s = 1.0f;
  for (int j = 0; j < CDIM; j += 4) {
    float4 a = *(const float4*)(cr + j);
    float4 w = *(const float4*)(wr + j);
    s = fmaf(a.x, w.x, s); s = fmaf(a.y, w.y, s);
    s = fmaf(a.z, w.z, s); s = fmaf(a.w, w.w, s);
  }
  cs[idx] = s;
}

// ---------------- RMS-norm * cs -> xn (M, C) bf16, one-pass via LDS ----------------
__global__ __launch_bounds__(256) void norm_kernel(const float* __restrict__ x,
                                                   const float* __restrict__ cs,
                                                   u16* __restrict__ xn) {
  __shared__ float xs[16][772];
  __shared__ float red[16][17];
  __shared__ float rfac[16];
  int n = blockIdx.y;
  int hw0 = blockIdx.x * 16;
  int b = n >> 3, t = n & 7;
  int tx = threadIdx.x, ty = threadIdx.y;
  const float* xb = x + ((size_t)b * CDIM * TDIM + t) * SDIM;
  float acc = 0.0f;
  for (int c = ty; c < CDIM; c += 16) {
    float v = xb[(size_t)c * (TDIM * SDIM) + hw0 + tx];
    xs[tx][c] = v;
    acc = fmaf(v, v, acc);
  }
  red[ty][tx] = acc;
  __syncthreads();
  if (ty == 0) {
    float s = 0.0f;
    #pragma unroll
    for (int j = 0; j < 16; j++) s += red[j][tx];
    rfac[tx] = rsqrtf(s * (1.0f / (float)CDIM) + 1e-6f);
  }
  __syncthreads();
  const float* csb = cs + (size_t)b * CDIM;
  int flat = ty * 16 + tx;
  #pragma unroll
  for (int i = 0; i < 6; i++) {
    int idx = i * 256 + flat;
    int row = idx / 96;
    int cseg = idx - row * 96;
    int c0 = cseg * 8;
    float rf = rfac[row];
    float4 a0 = *(const float4*)&xs[row][c0];
    float4 a1 = *(const float4*)&xs[row][c0 + 4];
    float4 w0 = *(const float4*)(csb + c0);
    float4 w1 = *(const float4*)(csb + c0 + 4);
    u16x8 ov;
    ov[0] = f2bf(a0.x * w0.x * rf); ov[1] = f2bf(a0.y * w0.y * rf);
    ov[2] = f2bf(a0.z * w0.z * rf); ov[3] = f2bf(a0.w * w0.w * rf);
    ov[4] = f2bf(a1.x * w1.x * rf); ov[5] = f2bf(a1.y * w1.y * rf);
    ov[6] = f2bf(a1.z * w1.z * rf); ov[7] = f2bf(a1.w * w1.w * rf);
    *(u16x8*)(xn + ((size_t)n * SDIM + hw0 + row) * CDIM + c0) = ov;
  }
}

// ---------------- f32 -> bf16 weight convert ----------------
__global__ __launch_bounds__(256) void convert_kernel(const float* __restrict__ src,
                                                      u16* __restrict__ dst, int count4) {
  int i = blockIdx.x * 256 + threadIdx.x;
  if (i < count4) {
    float4 v = *(const float4*)(src + (size_t)i * 4);
    u16* d = dst + (size_t)i * 4;
    d[0] = f2bf(v.x); d[1] = f2bf(v.y); d[2] = f2bf(v.z); d[3] = f2bf(v.w);
  }
}

// ---------------- m97-style MFMA GEMM core v2: C = A(M,K) * B(N,K)^T ----------------
// 128x128 tile, BK=64 (12 k-steps at K=768: half the barrier drains of BK=32).
// Staging: global_load_lds width=16 into linear LDS [128][64], with the global
// SOURCE 16B-chunk pre-swizzled (seg ^= row&7) and the SAME XOR applied on the
// ds_read side (rule: both-sides-or-neither). 16-lane frag reads then alias
// max 2 lanes/bank-slot (free).
__device__ __forceinline__ void gemm_bt_lds(const u16* __restrict__ A,
                                            const u16* __restrict__ B,
                                            int K, int m0, int n0, int tid,
                                            u16* ldsA, u16* ldsB,
                                            f32x4 acc[4][4]) {
  int lane = tid & 63;
  int wid = tid >> 6;
  int wm = (wid >> 1) * 64, wn = (wid & 1) * 64;
  int lr = lane & 15, lg = lane >> 4;
  // staging: wave covers rows [wid*32, wid*32+32), 4 issues of 8 rows x 8 segs.
  // lane l -> row (l>>3), seg_lds (l&7); source seg_g = (l&7) ^ (l>>3).
  const u16* gA = A + (size_t)(m0 + wid * 32 + (lane >> 3)) * K + (((lane & 7) ^ (lane >> 3)) * 8);
  const u16* gB = B + (size_t)(n0 + wid * 32 + (lane >> 3)) * K + (((lane & 7) ^ (lane >> 3)) * 8);
  u16* dA = ldsA + wid * 32 * 64;
  u16* dB = ldsB + wid * 32 * 64;
  for (int k0 = 0; k0 < K; k0 += 64) {
    __syncthreads();                       // prev reads done before overwrite
    #pragma unroll
    for (int is = 0; is < 4; is++) {
      __builtin_amdgcn_global_load_lds(
          (const __attribute__((address_space(1))) unsigned int*)(gA + (size_t)(is * 8) * K + k0),
          (__attribute__((address_space(3))) unsigned int*)(dA + is * 512),
          16, 0, 0);
      __builtin_amdgcn_global_load_lds(
          (const __attribute__((address_space(1))) unsigned int*)(gB + (size_t)(is * 8) * K + k0),
          (__attribute__((address_space(3))) unsigned int*)(dB + is * 512),
          16, 0, 0);
    }
    __syncthreads();                       // drain: loads visible
    #pragma unroll
    for (int kk = 0; kk < 2; kk++) {
      bf16x8 af[4], bfr[4];
      #pragma unroll
      for (int i = 0; i < 4; i++)
        af[i]  = *(const bf16x8*)&ldsA[(wm + i * 16 + lr) * 64 + (((lg + 4 * kk) ^ (lr & 7)) * 8)];
      #pragma unroll
      for (int j = 0; j < 4; j++)
        bfr[j] = *(const bf16x8*)&ldsB[(wn + j * 16 + lr) * 64 + (((lg + 4 * kk) ^ (lr & 7)) * 8)];
      #pragma unroll
      for (int i = 0; i < 4; i++)
        #pragma unroll
        for (int j = 0; j < 4; j++)
          acc[i][j] = __builtin_amdgcn_mfma_f32_16x16x32_bf16(af[i], bfr[j], acc[i][j], 0, 0, 0);
    }
  }
}

// XCD-chunk swizzle: grid = 8 XCD * 9 m-blocks * NBLK n-blocks (bijective).
__device__ __forceinline__ void swz_tile(int L, int& m0, int& n0) {
  int xcd = L & 7, loc = L >> 3;
  int nblk = loc / 9, mloc = loc - nblk * 9;
  m0 = (xcd * 9 + mloc) * 128;
  n0 = nblk * 128;
}

// ---------------- QKV GEMM with fused cosine-norm + RoPE epilogue ----------------
// part 0/1 (q/k): row-sum over e via 4 regs + 4 shfl_xor (16-lane group);
// RoPE pair (e, e+16) is register-local (j=0 <-> j=1); q gets sqrt(scale)*log2e,
// k gets sqrt(scale). part 2: v scattered transposed as before.
__global__ __launch_bounds__(256) void gemm_qkv(const u16* __restrict__ xn,
                                                const u16* __restrict__ wq,
                                                const float* __restrict__ pos,
                                                const float* __restrict__ freqs,
                                                const float* __restrict__ scale,
                                                u16* __restrict__ q,
                                                u16* __restrict__ k,
                                                u16* __restrict__ vt) {
  __shared__ u16 ldsA[128 * 64];
  __shared__ u16 ldsB[128 * 64];
  f32x4 acc[4][4] = {};
  int tid = threadIdx.x;
  int m0, n0;
  swz_tile(blockIdx.x, m0, n0);
  gemm_bt_lds(xn, wq, CDIM, m0, n0, tid, ldsA, ldsB, acc);
  int lane = tid & 63, wid = tid >> 6;
  int wm = (wid >> 1) * 64, wn = (wid & 1) * 64;
  int lr = lane & 15, rb = (lane >> 4) * 4;
  int part = n0 / CDIM;                    // block-uniform
  int h = ((n0 - part * CDIM) + wn) >> 6;  // wave-uniform head
  if (part < 2) {
    float fr = freqs[h * 8 + (lr & 7)];
    float sq = sqrtf(scale[h]) * (part == 0 ? 1.44269504f : 1.0f);
    u16* dst = (part == 0) ? q : k;
    #pragma unroll
    for (int i = 0; i < 4; i++)
      #pragma unroll
      for (int r = 0; r < 4; r++) {
        int m = m0 + wm + i * 16 + rb + r;
        int nidx = m / SDIM, sp = m - nidx * SDIM;
        int b = nidx >> 3;
        float2 pp = *(const float2*)&pos[((size_t)b * SDIM + sp) * 2];
        float th = (lr < 8 ? pp.x : pp.y) * fr;
        float sth, cth;
        __sincosf(th, &sth, &cth);
        float v0 = acc[0 + i][0][r] * 1.0f;  // keep indexing static
        float v1 = acc[i][1][r];
        float v2 = acc[i][2][r];
        float v3 = acc[i][3][r];
        v0 = acc[i][0][r];
        float ss = v0 * v0 + v1 * v1 + v2 * v2 + v3 * v3;
        ss += __shfl_xor(ss, 1); ss += __shfl_xor(ss, 2);
        ss += __shfl_xor(ss, 4); ss += __shfl_xor(ss, 8);
        float rs = sq * rsqrtf(ss + 1e-6f);
        v0 *= rs; v1 *= rs; v2 *= rs; v3 *= rs;
        float o0 = v0 * cth - v1 * sth;
        float o1 = v1 * cth + v0 * sth;
        u16* row = dst + ((size_t)(nidx * NHEAD + h) * SDIM + sp) * EDIM + lr;
        row[0]  = f2bf(o0); row[16] = f2bf(o1);
        row[32] = f2bf(v2); row[48] = f2bf(v3);
      }
  } else {
    #pragma unroll
    for (int i = 0; i < 4; i++)
      #pragma unroll
      for (int j = 0; j < 4; j++)
        #pragma unroll
        for (int r = 0; r < 4; r++) {
          int m = m0 + wm + i * 16 + rb + r;
          int nidx = m / SDIM, hw = m - nidx * SDIM;
          int e = j * 16 + lr;
          vt[((size_t)(nidx * NHEAD + h) * EDIM + e) * SDIM + hw] = f2bf(acc[i][j][r]);
        }
  }
}

// ---------------- MFMA flash attention v3 ----------------
// Logits bounded (|q.k| <= 10 after cosine-norm * sqrt(10)): NO max tracking,
// p = exp2(s) directly (log2e pre-folded into q). Swapped QK^T mfma(K,Q).
// Single-wave blocks, 48 q-rows each: grid 2304 = 8 XCD x 288, chunk-swizzled.
__global__ __launch_bounds__(64, 2) void attn_mfma(const u16* __restrict__ q,
                                                   const u16* __restrict__ k,
                                                   const u16* __restrict__ vt,
                                                   u16* __restrict__ o) {
  __shared__ u16 p_lds[48][72];
  int L = blockIdx.x;
  int cid = (L & 7) * 288 + (L >> 3);            // XCD-chunked bijective remap
  int nh_ = cid / 12;
  int qt = cid - nh_ * 12;
  int n = nh_ / NHEAD, h = nh_ - n * NHEAD;
  int lane = threadIdx.x;
  int lr = lane & 15, lg = lane >> 4;
  int qbase = qt * 48;

  const u16* qp = q + ((size_t)nh_ * SDIM + qbase) * EDIM;
  bf16x8 qa[3][2];
  #pragma unroll
  for (int f = 0; f < 3; f++) {
    qa[f][0] = *(const bf16x8*)(qp + (size_t)(f * 16 + lr) * EDIM + lg * 8);
    qa[f][1] = *(const bf16x8*)(qp + (size_t)(f * 16 + lr) * EDIM + 32 + lg * 8);
  }
  const u16* kb = k + (size_t)nh_ * SDIM * EDIM;
  const u16* vb = vt + (size_t)nh_ * EDIM * SDIM;

  float psum[3] = {0.0f, 0.0f, 0.0f};
  f32x4 oacc[3][4] = {};

  bf16x8 kf[4][2];
  #pragma unroll
  for (int j = 0; j < 4; j++) {
    const u16* kr = kb + (size_t)(j * 16 + lr) * EDIM + lg * 8;
    kf[j][0] = *(const bf16x8*)kr;
    kf[j][1] = *(const bf16x8*)(kr + 32);
  }

  #pragma unroll 1
  for (int kt = 0; kt < 9; kt++) {
    int s0 = kt * 64;
    // ---- V loads: in flight during QK^T + exp ----
    bf16x8 vf[2][4];
    #pragma unroll
    for (int ks = 0; ks < 2; ks++)
      #pragma unroll
      for (int et = 0; et < 4; et++)
        vf[ks][et] = *(const bf16x8*)(vb + (size_t)(et * 16 + lr) * SDIM + s0 + ks * 32 + lg * 8);
    // ---- swapped QK^T: S^T[kcol][qrow], lane owns qrow=lr, kcols j*16+lg*4+r ----
    #pragma unroll
    for (int f = 0; f < 3; f++) {
      f32x4 sfr[4] = {};
      #pragma unroll
      for (int j = 0; j < 4; j++) {
        sfr[j] = __builtin_amdgcn_mfma_f32_16x16x32_bf16(kf[j][0], qa[f][0], sfr[j], 0, 0, 0);
        sfr[j] = __builtin_amdgcn_mfma_f32_16x16x32_bf16(kf[j][1], qa[f][1], sfr[j], 0, 0, 0);
      }
      float fs = 0.0f;
      #pragma unroll
      for (int j = 0; j < 4; j++) {
        float p0 = exp2f(sfr[j][0]);
        float p1 = exp2f(sfr[j][1]);
        float p2 = exp2f(sfr[j][2]);
        float p3 = exp2f(sfr[j][3]);
        unsigned w0 = cvt_pk_bf16(p0, p1);
        unsigned w1 = cvt_pk_bf16(p2, p3);
        *(unsigned*)&p_lds[f * 16 + lr][j * 16 + lg * 4]     = w0;
        *(unsigned*)&p_lds[f * 16 + lr][j * 16 + lg * 4 + 2] = w1;
        fs += (p0 + p1) + (p2 + p3);
      }
      psum[f] += fs;
    }
    // ---- prefetch next K tile: in flight during PV ----
    if (kt < 8) {
      #pragma unroll
      for (int j = 0; j < 4; j++) {
        const u16* kr = kb + (size_t)(s0 + 64 + j * 16 + lr) * EDIM + lg * 8;
        kf[j][0] = *(const bf16x8*)kr;
        kf[j][1] = *(const bf16x8*)(kr + 32);
      }
    }
    // ---- PV: O += P(48x64) @ V(64x64) ----
    #pragma unroll
    for (int f = 0; f < 3; f++)
      #pragma unroll
      for (int ks = 0; ks < 2; ks++) {
        bf16x8 pa = *(const bf16x8*)&p_lds[f * 16 + lr][ks * 32 + lg * 8];
        #pragma unroll
        for (int et = 0; et < 4; et++)
          oacc[f][et] = __builtin_amdgcn_mfma_f32_16x16x32_bf16(pa, vf[ks][et], oacc[f][et], 0, 0, 0);
      }
  }
  // ---- epilogue: one reduce per frag, distribute inv, store ----
  u16* ob = o + ((size_t)n * SDIM + qbase) * CDIM + h * EDIM;
  #pragma unroll
  for (int f = 0; f < 3; f++) {
    float s = psum[f];
    s += __shfl_xor(s, 16);
    s += __shfl_xor(s, 32);
    float inv = 1.0f / s;                        // valid for q-row = lr
    #pragma unroll
    for (int r = 0; r < 4; r++) {
      float invr = __shfl(inv, lg * 4 + r);      // inv for q-row = lg*4+r
      #pragma unroll
      for (int et = 0; et < 4; et++)
        ob[(size_t)(f * 16 + lg * 4 + r) * CDIM + et * 16 + lr] = f2bf(oacc[f][et][r] * invr);
    }
  }
}

// ---------------- out projection + skip: out = o @ wo^T + x ----------------
__global__ __launch_bounds__(256) void gemm_proj(const u16* __restrict__ o,
                                                 const u16* __restrict__ wo,
                                                 const float* __restrict__ x,
                                                 float* __restrict__ out) {
  __shared__ u16 ldsA[128 * 64];
  __shared__ u16 ldsB[128 * 64];
  f32x4 acc[4][4] = {};
  int tid = threadIdx.x;
  int m0, n0;
  swz_tile(blockIdx.x, m0, n0);
  gemm_bt_lds(o, wo, CDIM, m0, n0, tid, ldsA, ldsB, acc);
  int lane = tid & 63, wid = tid >> 6;
  int wm = (wid >> 1) * 64, wn = (wid & 1) * 64;
  int lr = lane & 15, rb = (lane >> 4) * 4;
  #pragma unroll
  for (int i = 0; i < 4; i++)
    #pragma unroll
    for (int j = 0; j < 4; j++)
      #pragma unroll
      for (int r = 0; r < 4; r++) {
        int m = m0 + wm + i * 16 + rb + r;
        int jj = n0 + wn + j * 16 + lr;
        int nidx = m / SDIM, hw = m - nidx * SDIM;
        int b = nidx >> 3, t = nidx & 7;
        size_t oi = ((size_t)(b * CDIM + jj) * TDIM + t) * SDIM + hw;
        out[oi] = acc[i][j][r] + x[oi];
      }
}

extern "C" void kernel_launch(void* const* d_in, const int* in_sizes, int n_in,
                              void* d_out, int out_size, void* d_ws, size_t ws_size,
                              hipStream_t stream) {
  const float* x      = (const float*)d_in[0];
  const float* pos    = (const float*)d_in[1];
  const float* cond   = (const float*)d_in[2];
  const float* norm_w = (const float*)d_in[3];
  const float* qkv_w  = (const float*)d_in[4];
  const float* scale  = (const float*)d_in[5];
  const float* out_w  = (const float*)d_in[6];
  const float* freqs  = (const float*)d_in[7];
  float* out = (float*)d_out;

  char* ws = (char*)d_ws;
  size_t off = 0;
  auto alloc = [&](size_t bytes) -> char* {
    char* p = ws + off;
    off = (off + bytes + 255) & ~(size_t)255;
    return p;
  };
  float* cs  = (float*)alloc(2 * CDIM * sizeof(float));
  u16* wq    = (u16*)alloc((size_t)QKVN * CDIM * 2);
  u16* wo    = (u16*)alloc((size_t)CDIM * CDIM * 2);
  u16* xn    = (u16*)alloc((size_t)MDIM * CDIM * 2);
  u16* qb    = (u16*)alloc((size_t)MDIM * CDIM * 2);
  u16* kb    = (u16*)alloc((size_t)MDIM * CDIM * 2);
  u16* vt    = (u16*)alloc((size_t)MDIM * CDIM * 2);
  u16* ob    = (u16*)alloc((size_t)MDIM * CDIM * 2);

  convert_kernel<<<dim3((QKVN * CDIM / 4 + 255) / 256), dim3(256), 0, stream>>>(qkv_w, wq, QKVN * CDIM / 4);
  convert_kernel<<<dim3((CDIM * CDIM / 4 + 255) / 256), dim3(256), 0, stream>>>(out_w, wo, CDIM * CDIM / 4);
  cs_kernel<<<dim3(6), dim3(256), 0, stream>>>(cond, norm_w, cs);
  norm_kernel<<<dim3(SDIM / 16, NROW), dim3(16, 16), 0, stream>>>(x, cs, xn);
  gemm_qkv<<<dim3(8 * 9 * (QKVN / 128)), dim3(256), 0, stream>>>(xn, wq, pos, freqs, scale, qb, kb, vt);
  attn_mfma<<<dim3(2304), dim3(64), 0, stream>>>(qb, kb, vt, ob);
  gemm_proj<<<dim3(8 * 9 * (CDIM / 128)), dim3(256), 0, stream>>>(ob, wo, x, out);
}